// Round 1
// baseline (901.944 us; speedup 1.0000x reference)
//
#include <hip/hip_runtime.h>
#include <hip/hip_bf16.h>

#define N_NODES 100000
#define N_EDGES 600000
#define HID 128
// y row = 256 floats: [0:128) = x@W1[0:128] (src role), [128:256) = x@W1[128:256] (tgt role)

// ---------------- helpers ----------------
__device__ inline float2 load2f(const float* p) { return *(const float2*)p; }
__device__ inline float2 load2f(const __hip_bfloat16* p) {
    __hip_bfloat162 v = *(const __hip_bfloat162*)p;
    return make_float2(__bfloat162float(v.x), __bfloat162float(v.y));
}
__device__ inline void store_y(float* p, float v) { *p = v; }
__device__ inline void store_y(__hip_bfloat16* p, float v) { *p = __float2bfloat16(v); }

// ---------------- K1: out = x, sum_exp = 0 ----------------
__global__ __launch_bounds__(256) void k_init(const float4* __restrict__ x4,
                                              float4* __restrict__ out4,
                                              float* __restrict__ sum_exp, int n4)
{
    int i = blockIdx.x * blockDim.x + threadIdx.x;
    int stride = gridDim.x * blockDim.x;
    for (int j = i; j < n4; j += stride) out4[j] = x4[j];
    for (int j = i; j < N_NODES; j += stride) sum_exp[j] = 0.f;
}

// ---------------- K2: y[i, 0:256] = x[i] @ [W1a | W1b] ----------------
// M=100000, N=256, K=128. 64x64 tile, 256 threads, 4x4 micro-tile, KT=32.
template<typename YT>
__global__ __launch_bounds__(256) void k_gemm(const float* __restrict__ x,
                                              const float* __restrict__ W1,
                                              YT* __restrict__ y)
{
    __shared__ float As[32][68];  // [k][m], padded to 68 (16B-aligned rows, conflict-safe)
    __shared__ float Bs[32][68];  // [k][n]
    const int tid = threadIdx.x;
    const int bm = blockIdx.x * 64;
    const int bn = blockIdx.y * 64;
    const int tm = (tid >> 4) * 4;
    const int tn = (tid & 15) * 4;

    float acc[4][4] = {};

    for (int k0 = 0; k0 < HID; k0 += 32) {
        // A tile: As[k][m] = x[(bm+m)*128 + k0+k]  (rows of 32 consecutive floats -> coalesced)
        #pragma unroll
        for (int t = tid; t < 64 * 32; t += 256) {
            int m = t >> 5, k = t & 31;
            int gm = bm + m;
            As[k][m] = (gm < N_NODES) ? x[(size_t)gm * HID + k0 + k] : 0.f;
        }
        // B tile: Bs[k][n] = Wcat[k0+k][bn+n]; Wcat[k][c] = (c<128) ? W1[k][c] : W1[128+k][c-128]
        #pragma unroll
        for (int t = tid; t < 32 * 64; t += 256) {
            int k = t >> 6, n = t & 63;
            int gc = bn + n, gk = k0 + k;
            Bs[k][n] = (gc < HID) ? W1[gk * HID + gc] : W1[(HID + gk) * HID + (gc - HID)];
        }
        __syncthreads();
        #pragma unroll
        for (int k = 0; k < 32; ++k) {
            float4 a = *(const float4*)&As[k][tm];
            float4 b = *(const float4*)&Bs[k][tn];
            acc[0][0] = fmaf(a.x, b.x, acc[0][0]); acc[0][1] = fmaf(a.x, b.y, acc[0][1]);
            acc[0][2] = fmaf(a.x, b.z, acc[0][2]); acc[0][3] = fmaf(a.x, b.w, acc[0][3]);
            acc[1][0] = fmaf(a.y, b.x, acc[1][0]); acc[1][1] = fmaf(a.y, b.y, acc[1][1]);
            acc[1][2] = fmaf(a.y, b.z, acc[1][2]); acc[1][3] = fmaf(a.y, b.w, acc[1][3]);
            acc[2][0] = fmaf(a.z, b.x, acc[2][0]); acc[2][1] = fmaf(a.z, b.y, acc[2][1]);
            acc[2][2] = fmaf(a.z, b.z, acc[2][2]); acc[2][3] = fmaf(a.z, b.w, acc[2][3]);
            acc[3][0] = fmaf(a.w, b.x, acc[3][0]); acc[3][1] = fmaf(a.w, b.y, acc[3][1]);
            acc[3][2] = fmaf(a.w, b.z, acc[3][2]); acc[3][3] = fmaf(a.w, b.w, acc[3][3]);
        }
        __syncthreads();
    }

    #pragma unroll
    for (int i = 0; i < 4; ++i) {
        int r = bm + tm + i;
        if (r >= N_NODES) break;
        #pragma unroll
        for (int j = 0; j < 4; ++j) {
            int c = bn + tn + j;
            store_y(&y[(size_t)r * 256 + c], acc[i][j]);
        }
    }
}

// ---------------- K3: per-edge score + exp + segment-sum ----------------
// one wave (64 lanes) per edge; lane handles cols 2*lane, 2*lane+1
template<typename YT>
__global__ __launch_bounds__(256) void k_scores(const YT* __restrict__ y,
                                                const int* __restrict__ ei,
                                                const float* __restrict__ ew,
                                                const float* __restrict__ W1,
                                                const float* __restrict__ b1,
                                                const float* __restrict__ W2,
                                                const float* __restrict__ b2,
                                                float* __restrict__ exp_scores,
                                                float* __restrict__ sum_exp)
{
    int wave = (blockIdx.x * blockDim.x + threadIdx.x) >> 6;
    int lane = threadIdx.x & 63;
    if (wave >= N_EDGES) return;
    int e = wave;
    int src = ei[e];
    int tgt = ei[N_EDGES + e];
    float w = ew[e];
    int c0 = lane * 2;

    float2 a  = load2f(y + (size_t)src * 256 + c0);          // y1[src]
    float2 bb = load2f(y + (size_t)tgt * 256 + 128 + c0);    // y2[tgt]
    float2 wr = *(const float2*)&W1[256 * HID + c0];         // W1 row 256 (edge-weight row)
    float2 bv = *(const float2*)&b1[c0];
    float h0 = fmaxf(a.x + bb.x + w * wr.x + bv.x, 0.f);
    float h1 = fmaxf(a.y + bb.y + w * wr.y + bv.y, 0.f);
    float2 w2 = *(const float2*)&W2[c0];
    float p = h0 * w2.x + h1 * w2.y;

    #pragma unroll
    for (int off = 32; off > 0; off >>= 1) p += __shfl_down(p, off, 64);

    if (lane == 0) {
        float es = expf(p + b2[0]);
        exp_scores[e] = es;
        atomicAdd(&sum_exp[tgt], es);
    }
}

// ---------------- K4: out[tgt] += alpha * x[src] ----------------
__global__ __launch_bounds__(256) void k_scatter(const float* __restrict__ x,
                                                 const int* __restrict__ ei,
                                                 const float* __restrict__ exp_scores,
                                                 const float* __restrict__ sum_exp,
                                                 float* __restrict__ out)
{
    int wave = (blockIdx.x * blockDim.x + threadIdx.x) >> 6;
    int lane = threadIdx.x & 63;
    if (wave >= N_EDGES) return;
    int e = wave;
    int src = ei[e];
    int tgt = ei[N_EDGES + e];
    float alpha = exp_scores[e] / fmaxf(sum_exp[tgt], 1e-12f);
    int c0 = lane * 2;
    float2 v = *(const float2*)&x[(size_t)src * HID + c0];
    atomicAdd(&out[(size_t)tgt * HID + c0],     alpha * v.x);
    atomicAdd(&out[(size_t)tgt * HID + c0 + 1], alpha * v.y);
}

// ---------------- launch ----------------
extern "C" void kernel_launch(void* const* d_in, const int* in_sizes, int n_in,
                              void* d_out, int out_size, void* d_ws, size_t ws_size,
                              hipStream_t stream) {
    const float* x  = (const float*)d_in[0];
    const int*   ei = (const int*)d_in[1];
    const float* ew = (const float*)d_in[2];
    const float* W1 = (const float*)d_in[3];
    const float* b1 = (const float*)d_in[4];
    const float* W2 = (const float*)d_in[5];
    const float* b2 = (const float*)d_in[6];
    float* out = (float*)d_out;
    char* ws = (char*)d_ws;

    const size_t y_f32_bytes  = (size_t)N_NODES * 256 * sizeof(float);
    const size_t y_bf16_bytes = (size_t)N_NODES * 256 * sizeof(__hip_bfloat16);
    const size_t es_bytes     = (size_t)N_EDGES * sizeof(float);
    const size_t se_bytes     = (size_t)N_NODES * sizeof(float);

    const int n4 = N_NODES * HID / 4;
    const dim3 gemm_grid((N_NODES + 63) / 64, 256 / 64);
    const int edge_blocks = (N_EDGES + 3) / 4;  // 4 waves per 256-thread block

    bool use_f32 = (ws_size >= y_f32_bytes + es_bytes + se_bytes);

    if (use_f32) {
        float* y         = (float*)ws;
        float* exp_sc    = (float*)(ws + y_f32_bytes);
        float* sum_exp   = (float*)(ws + y_f32_bytes + es_bytes);

        hipLaunchKernelGGL(k_init, dim3((n4 + 255) / 256), dim3(256), 0, stream,
                           (const float4*)x, (float4*)out, sum_exp, n4);
        hipLaunchKernelGGL(k_gemm<float>, gemm_grid, dim3(256), 0, stream, x, W1, y);
        hipLaunchKernelGGL(k_scores<float>, dim3(edge_blocks), dim3(256), 0, stream,
                           y, ei, ew, W1, b1, W2, b2, exp_sc, sum_exp);
        hipLaunchKernelGGL(k_scatter, dim3(edge_blocks), dim3(256), 0, stream,
                           x, ei, exp_sc, sum_exp, out);
    } else {
        __hip_bfloat16* y = (__hip_bfloat16*)ws;
        float* exp_sc     = (float*)(ws + y_bf16_bytes);
        float* sum_exp    = (float*)(ws + y_bf16_bytes + es_bytes);

        hipLaunchKernelGGL(k_init, dim3((n4 + 255) / 256), dim3(256), 0, stream,
                           (const float4*)x, (float4*)out, sum_exp, n4);
        hipLaunchKernelGGL(k_gemm<__hip_bfloat16>, gemm_grid, dim3(256), 0, stream, x, W1, y);
        hipLaunchKernelGGL(k_scores<__hip_bfloat16>, dim3(edge_blocks), dim3(256), 0, stream,
                           y, ei, ew, W1, b1, W2, b2, exp_sc, sum_exp);
        hipLaunchKernelGGL(k_scatter, dim3(edge_blocks), dim3(256), 0, stream,
                           x, ei, exp_sc, sum_exp, out);
    }
}

// Round 2
// 666.333 us; speedup vs baseline: 1.3536x; 1.3536x over previous
//
#include <hip/hip_runtime.h>
#include <hip/hip_bf16.h>

#define N_NODES 100000
#define N_EDGES 600000
#define HID 128
// y row = 256 cols: [0:128) = x@W1[0:128] (src role), [128:256) = x@W1[128:256] (tgt role)

// ---------------- helpers ----------------
__device__ inline float2 load2f(const float* p) { return *(const float2*)p; }
__device__ inline float2 load2f(const __hip_bfloat16* p) {
    __hip_bfloat162 v = *(const __hip_bfloat162*)p;
    return make_float2(__bfloat162float(v.x), __bfloat162float(v.y));
}
__device__ inline void store_y(float* p, float v) { *p = v; }
__device__ inline void store_y(__hip_bfloat16* p, float v) { *p = __float2bfloat16(v); }

// ---------------- K-gemm: y[i, 0:256] = x[i] @ [W1a | W1b] ----------------
template<typename YT>
__global__ __launch_bounds__(256) void k_gemm(const float* __restrict__ x,
                                              const float* __restrict__ W1,
                                              YT* __restrict__ y)
{
    __shared__ float As[32][68];
    __shared__ float Bs[32][68];
    const int tid = threadIdx.x;
    const int bm = blockIdx.x * 64;
    const int bn = blockIdx.y * 64;
    const int tm = (tid >> 4) * 4;
    const int tn = (tid & 15) * 4;

    float acc[4][4] = {};

    for (int k0 = 0; k0 < HID; k0 += 32) {
        #pragma unroll
        for (int t = tid; t < 64 * 32; t += 256) {
            int m = t >> 5, k = t & 31;
            int gm = bm + m;
            As[k][m] = (gm < N_NODES) ? x[(size_t)gm * HID + k0 + k] : 0.f;
        }
        #pragma unroll
        for (int t = tid; t < 32 * 64; t += 256) {
            int k = t >> 6, n = t & 63;
            int gc = bn + n, gk = k0 + k;
            Bs[k][n] = (gc < HID) ? W1[gk * HID + gc] : W1[(HID + gk) * HID + (gc - HID)];
        }
        __syncthreads();
        #pragma unroll
        for (int k = 0; k < 32; ++k) {
            float4 a = *(const float4*)&As[k][tm];
            float4 b = *(const float4*)&Bs[k][tn];
            acc[0][0] = fmaf(a.x, b.x, acc[0][0]); acc[0][1] = fmaf(a.x, b.y, acc[0][1]);
            acc[0][2] = fmaf(a.x, b.z, acc[0][2]); acc[0][3] = fmaf(a.x, b.w, acc[0][3]);
            acc[1][0] = fmaf(a.y, b.x, acc[1][0]); acc[1][1] = fmaf(a.y, b.y, acc[1][1]);
            acc[1][2] = fmaf(a.y, b.z, acc[1][2]); acc[1][3] = fmaf(a.y, b.w, acc[1][3]);
            acc[2][0] = fmaf(a.z, b.x, acc[2][0]); acc[2][1] = fmaf(a.z, b.y, acc[2][1]);
            acc[2][2] = fmaf(a.z, b.z, acc[2][2]); acc[2][3] = fmaf(a.z, b.w, acc[2][3]);
            acc[3][0] = fmaf(a.w, b.x, acc[3][0]); acc[3][1] = fmaf(a.w, b.y, acc[3][1]);
            acc[3][2] = fmaf(a.w, b.z, acc[3][2]); acc[3][3] = fmaf(a.w, b.w, acc[3][3]);
        }
        __syncthreads();
    }

    #pragma unroll
    for (int i = 0; i < 4; ++i) {
        int r = bm + tm + i;
        if (r >= N_NODES) break;
        #pragma unroll
        for (int j = 0; j < 4; ++j) {
            int c = bn + tn + j;
            store_y(&y[(size_t)r * 256 + c], acc[i][j]);
        }
    }
}

// ---------------- CSR build ----------------
__global__ __launch_bounds__(256) void k_count(const int* __restrict__ ei,
                                               int* __restrict__ deg)
{
    int e = blockIdx.x * blockDim.x + threadIdx.x;
    if (e < N_EDGES) atomicAdd(&deg[ei[N_EDGES + e]], 1);
}

// single-block exclusive scan of deg[N_NODES] -> rowptr[N_NODES+1], cursor copy
__global__ __launch_bounds__(1024) void k_scan(const int* __restrict__ deg,
                                               int* __restrict__ rowptr,
                                               int* __restrict__ cursor)
{
    __shared__ int sdata[1024];
    const int CH = (N_NODES + 1023) / 1024;  // 98
    int t = threadIdx.x;
    int base = t * CH;
    int s = 0;
    for (int i = 0; i < CH; ++i) {
        int idx = base + i;
        if (idx < N_NODES) s += deg[idx];
    }
    sdata[t] = s;
    __syncthreads();
    for (int off = 1; off < 1024; off <<= 1) {
        int v = (t >= off) ? sdata[t - off] : 0;
        __syncthreads();
        sdata[t] += v;
        __syncthreads();
    }
    int run = sdata[t] - s;  // exclusive prefix
    for (int i = 0; i < CH; ++i) {
        int idx = base + i;
        if (idx < N_NODES) {
            rowptr[idx] = run;
            cursor[idx] = run;
            run += deg[idx];
        }
    }
    if (t == 1023) rowptr[N_NODES] = sdata[1023];
}

__global__ __launch_bounds__(256) void k_fill(const int* __restrict__ ei,
                                              const float* __restrict__ ew,
                                              int* __restrict__ cursor,
                                              int* __restrict__ esrc,
                                              float* __restrict__ ewb)
{
    int e = blockIdx.x * blockDim.x + threadIdx.x;
    if (e >= N_EDGES) return;
    int tgt = ei[N_EDGES + e];
    int pos = atomicAdd(&cursor[tgt], 1);
    esrc[pos] = ei[e];
    ewb[pos] = ew[e];
}

// ---------------- fused scores + online-softmax + aggregation ----------------
// one wave per node; lane handles cols 2*lane, 2*lane+1
// out[n] = x[n] + (sum_e es_e * x[src_e]) / (sum_e es_e)
template<typename YT>
__global__ __launch_bounds__(256) void k_fused(const YT* __restrict__ y,
                                               const int* __restrict__ rowptr,
                                               const int* __restrict__ esrc,
                                               const float* __restrict__ ewb,
                                               const float* __restrict__ x,
                                               const float* __restrict__ W1,
                                               const float* __restrict__ b1,
                                               const float* __restrict__ W2,
                                               const float* __restrict__ b2,
                                               float* __restrict__ out)
{
    int n = (blockIdx.x * blockDim.x + threadIdx.x) >> 6;
    int lane = threadIdx.x & 63;
    if (n >= N_NODES) return;
    int c0 = lane * 2;

    float2 y2 = load2f(y + (size_t)n * 256 + 128 + c0);
    float2 bv = *(const float2*)&b1[c0];
    float2 pre = make_float2(y2.x + bv.x, y2.y + bv.y);
    float2 wr = *(const float2*)&W1[256 * HID + c0];
    float2 w2 = *(const float2*)&W2[c0];
    float b2v = b2[0];

    int beg = rowptr[n], end = rowptr[n + 1];
    float accx = 0.f, accy = 0.f, denom = 0.f;

    for (int i = beg; i < end; ++i) {
        int src = esrc[i];
        float w = ewb[i];
        // issue both gathers up front (independent)
        float2 a  = load2f(y + (size_t)src * 256 + c0);
        float2 xv = *(const float2*)&x[(size_t)src * HID + c0];
        float h0 = fmaxf(a.x + pre.x + w * wr.x, 0.f);
        float h1 = fmaxf(a.y + pre.y + w * wr.y, 0.f);
        float p = h0 * w2.x + h1 * w2.y;
        #pragma unroll
        for (int m = 32; m > 0; m >>= 1) p += __shfl_xor(p, m, 64);
        float es = expf(p + b2v);
        accx = fmaf(es, xv.x, accx);
        accy = fmaf(es, xv.y, accy);
        denom += es;
    }

    float2 xt = *(const float2*)&x[(size_t)n * HID + c0];
    float inv = 1.0f / fmaxf(denom, 1e-12f);
    out[(size_t)n * HID + c0]     = xt.x + accx * inv;
    out[(size_t)n * HID + c0 + 1] = xt.y + accy * inv;
}

// ---------------- launch ----------------
extern "C" void kernel_launch(void* const* d_in, const int* in_sizes, int n_in,
                              void* d_out, int out_size, void* d_ws, size_t ws_size,
                              hipStream_t stream) {
    const float* x  = (const float*)d_in[0];
    const int*   ei = (const int*)d_in[1];
    const float* ew = (const float*)d_in[2];
    const float* W1 = (const float*)d_in[3];
    const float* b1 = (const float*)d_in[4];
    const float* W2 = (const float*)d_in[5];
    const float* b2 = (const float*)d_in[6];
    float* out = (float*)d_out;
    char* ws = (char*)d_ws;

    const size_t y_f32_bytes  = (size_t)N_NODES * 256 * sizeof(float);
    const size_t y_bf16_bytes = (size_t)N_NODES * 256 * sizeof(__hip_bfloat16);
    // CSR arrays
    const size_t deg_b    = (size_t)N_NODES * 4;
    const size_t rowptr_b = (size_t)(N_NODES + 1) * 4 + 12;  // pad to 16B align
    const size_t cursor_b = (size_t)N_NODES * 4;
    const size_t esrc_b   = (size_t)N_EDGES * 4;
    const size_t csr_b    = deg_b + rowptr_b + cursor_b + esrc_b + (size_t)N_EDGES * 4;

    const dim3 gemm_grid((N_NODES + 63) / 64, 256 / 64);
    const int edge_blocks = (N_EDGES + 255) / 256;
    const int node_wave_blocks = (N_NODES * 64 + 255) / 256;  // 4 waves/block

    bool use_f32 = (ws_size >= y_f32_bytes + csr_b);
    size_t y_bytes = use_f32 ? y_f32_bytes : y_bf16_bytes;

    char* p = ws;
    void* y_ptr   = (void*)p;            p += y_bytes;
    int* deg      = (int*)p;             p += deg_b;
    int* rowptr   = (int*)p;             p += rowptr_b;
    int* cursor   = (int*)p;             p += cursor_b;
    int* esrc     = (int*)p;             p += esrc_b;
    float* ewb    = (float*)p;

    hipMemsetAsync(deg, 0, deg_b, stream);
    hipLaunchKernelGGL(k_count, dim3(edge_blocks), dim3(256), 0, stream, ei, deg);
    hipLaunchKernelGGL(k_scan, dim3(1), dim3(1024), 0, stream, deg, rowptr, cursor);
    hipLaunchKernelGGL(k_fill, dim3(edge_blocks), dim3(256), 0, stream,
                       ei, ew, cursor, esrc, ewb);

    if (use_f32) {
        float* y = (float*)y_ptr;
        hipLaunchKernelGGL(k_gemm<float>, gemm_grid, dim3(256), 0, stream, x, W1, y);
        hipLaunchKernelGGL(k_fused<float>, dim3(node_wave_blocks), dim3(256), 0, stream,
                           y, rowptr, esrc, ewb, x, W1, b1, W2, b2, out);
    } else {
        __hip_bfloat16* y = (__hip_bfloat16*)y_ptr;
        hipLaunchKernelGGL(k_gemm<__hip_bfloat16>, gemm_grid, dim3(256), 0, stream, x, W1, y);
        hipLaunchKernelGGL(k_fused<__hip_bfloat16>, dim3(node_wave_blocks), dim3(256), 0, stream,
                           y, rowptr, esrc, ewb, x, W1, b1, W2, b2, out);
    }
}

// Round 3
// 430.449 us; speedup vs baseline: 2.0954x; 1.5480x over previous
//
#include <hip/hip_runtime.h>
#include <hip/hip_bf16.h>

#define N_NODES 100000
#define N_EDGES 600000
#define HID 128
#define SCAN_NB ((N_NODES + 255) / 256)   // 391
// y row = 256 cols: [0:128) = x@W1[0:128] (src role), [128:256) = x@W1[128:256] (tgt role)

// ---------------- helpers ----------------
__device__ inline float2 load2f(const float* p) { return *(const float2*)p; }
__device__ inline float2 load2f(const __hip_bfloat16* p) {
    __hip_bfloat162 v = *(const __hip_bfloat162*)p;
    return make_float2(__bfloat162float(v.x), __bfloat162float(v.y));
}
__device__ inline void store_y(float* p, float v) { *p = v; }
__device__ inline void store_y(__hip_bfloat16* p, float v) { *p = __float2bfloat16(v); }

// ---------------- K-gemm: y[i, 0:256] = x[i] @ [W1a | W1b] ----------------
template<typename YT>
__global__ __launch_bounds__(256) void k_gemm(const float* __restrict__ x,
                                              const float* __restrict__ W1,
                                              YT* __restrict__ y)
{
    __shared__ float As[32][68];
    __shared__ float Bs[32][68];
    const int tid = threadIdx.x;
    const int bm = blockIdx.x * 64;
    const int bn = blockIdx.y * 64;
    const int tm = (tid >> 4) * 4;
    const int tn = (tid & 15) * 4;

    float acc[4][4] = {};

    for (int k0 = 0; k0 < HID; k0 += 32) {
        #pragma unroll
        for (int t = tid; t < 64 * 32; t += 256) {
            int m = t >> 5, k = t & 31;
            int gm = bm + m;
            As[k][m] = (gm < N_NODES) ? x[(size_t)gm * HID + k0 + k] : 0.f;
        }
        #pragma unroll
        for (int t = tid; t < 32 * 64; t += 256) {
            int k = t >> 6, n = t & 63;
            int gc = bn + n, gk = k0 + k;
            Bs[k][n] = (gc < HID) ? W1[gk * HID + gc] : W1[(HID + gk) * HID + (gc - HID)];
        }
        __syncthreads();
        #pragma unroll
        for (int k = 0; k < 32; ++k) {
            float4 a = *(const float4*)&As[k][tm];
            float4 b = *(const float4*)&Bs[k][tn];
            acc[0][0] = fmaf(a.x, b.x, acc[0][0]); acc[0][1] = fmaf(a.x, b.y, acc[0][1]);
            acc[0][2] = fmaf(a.x, b.z, acc[0][2]); acc[0][3] = fmaf(a.x, b.w, acc[0][3]);
            acc[1][0] = fmaf(a.y, b.x, acc[1][0]); acc[1][1] = fmaf(a.y, b.y, acc[1][1]);
            acc[1][2] = fmaf(a.y, b.z, acc[1][2]); acc[1][3] = fmaf(a.y, b.w, acc[1][3]);
            acc[2][0] = fmaf(a.z, b.x, acc[2][0]); acc[2][1] = fmaf(a.z, b.y, acc[2][1]);
            acc[2][2] = fmaf(a.z, b.z, acc[2][2]); acc[2][3] = fmaf(a.z, b.w, acc[2][3]);
            acc[3][0] = fmaf(a.w, b.x, acc[3][0]); acc[3][1] = fmaf(a.w, b.y, acc[3][1]);
            acc[3][2] = fmaf(a.w, b.z, acc[3][2]); acc[3][3] = fmaf(a.w, b.w, acc[3][3]);
        }
        __syncthreads();
    }

    #pragma unroll
    for (int i = 0; i < 4; ++i) {
        int r = bm + tm + i;
        if (r >= N_NODES) break;
        #pragma unroll
        for (int j = 0; j < 4; ++j) {
            int c = bn + tn + j;
            store_y(&y[(size_t)r * 256 + c], acc[i][j]);
        }
    }
}

// ---------------- CSR build ----------------
__global__ __launch_bounds__(256) void k_count(const int* __restrict__ ei,
                                               int* __restrict__ deg)
{
    int e = blockIdx.x * blockDim.x + threadIdx.x;
    if (e < N_EDGES) atomicAdd(&deg[ei[N_EDGES + e]], 1);
}

// phase A: per-block sum of deg chunk
__global__ __launch_bounds__(256) void k_partial(const int* __restrict__ deg,
                                                 int* __restrict__ partial)
{
    __shared__ int s[256];
    int t = threadIdx.x;
    int idx = blockIdx.x * 256 + t;
    s[t] = (idx < N_NODES) ? deg[idx] : 0;
    __syncthreads();
    #pragma unroll
    for (int off = 128; off > 0; off >>= 1) {
        if (t < off) s[t] += s[t + off];
        __syncthreads();
    }
    if (t == 0) partial[blockIdx.x] = s[0];
}

// phase B: single block scans SCAN_NB partials -> exclusive pbase
__global__ __launch_bounds__(512) void k_scanp(const int* __restrict__ partial,
                                               int* __restrict__ pbase)
{
    __shared__ int s[512];
    int t = threadIdx.x;
    int v = (t < SCAN_NB) ? partial[t] : 0;
    s[t] = v;
    __syncthreads();
    #pragma unroll
    for (int off = 1; off < 512; off <<= 1) {
        int u = (t >= off) ? s[t - off] : 0;
        __syncthreads();
        s[t] += u;
        __syncthreads();
    }
    if (t < SCAN_NB) pbase[t] = s[t] - v;
}

// phase C: local exclusive scan + block base -> rowptr, cursor
__global__ __launch_bounds__(256) void k_rowptr(const int* __restrict__ deg,
                                                const int* __restrict__ pbase,
                                                int* __restrict__ rowptr,
                                                int* __restrict__ cursor)
{
    __shared__ int s[256];
    int t = threadIdx.x;
    int b = blockIdx.x;
    int idx = b * 256 + t;
    int v = (idx < N_NODES) ? deg[idx] : 0;
    s[t] = v;
    __syncthreads();
    #pragma unroll
    for (int off = 1; off < 256; off <<= 1) {
        int u = (t >= off) ? s[t - off] : 0;
        __syncthreads();
        s[t] += u;
        __syncthreads();
    }
    if (idx < N_NODES) {
        int r = pbase[b] + s[t] - v;
        rowptr[idx] = r;
        cursor[idx] = r;
    }
    if (idx == 0) rowptr[N_NODES] = N_EDGES;
}

__global__ __launch_bounds__(256) void k_fill(const int* __restrict__ ei,
                                              const float* __restrict__ ew,
                                              int* __restrict__ cursor,
                                              int* __restrict__ esrc,
                                              float* __restrict__ ewb)
{
    int e = blockIdx.x * blockDim.x + threadIdx.x;
    if (e >= N_EDGES) return;
    int tgt = ei[N_EDGES + e];
    int pos = atomicAdd(&cursor[tgt], 1);
    esrc[pos] = ei[e];
    ewb[pos] = ew[e];
}

// ---------------- fused scores + softmax + aggregation ----------------
// one wave per node; lane handles cols 2*lane, 2*lane+1
// out[n] = x[n] + (sum_e es_e * x[src_e]) / (sum_e es_e)
template<typename YT>
__global__ __launch_bounds__(256) void k_fused(const YT* __restrict__ y,
                                               const int* __restrict__ rowptr,
                                               const int* __restrict__ esrc,
                                               const float* __restrict__ ewb,
                                               const float* __restrict__ x,
                                               const float* __restrict__ W1,
                                               const float* __restrict__ b1,
                                               const float* __restrict__ W2,
                                               const float* __restrict__ b2,
                                               float* __restrict__ out)
{
    int n = (blockIdx.x * blockDim.x + threadIdx.x) >> 6;
    int lane = threadIdx.x & 63;
    if (n >= N_NODES) return;
    int c0 = lane * 2;

    float2 y2 = load2f(y + (size_t)n * 256 + 128 + c0);
    float2 bv = *(const float2*)&b1[c0];
    float2 pre = make_float2(y2.x + bv.x, y2.y + bv.y);
    float2 wr = *(const float2*)&W1[256 * HID + c0];
    float2 w2 = *(const float2*)&W2[c0];
    float b2v = b2[0];

    int beg = rowptr[n], end = rowptr[n + 1];
    float accx = 0.f, accy = 0.f, denom = 0.f;

    for (int i = beg; i < end; ++i) {
        int src = esrc[i];
        float w = ewb[i];
        float2 a  = load2f(y + (size_t)src * 256 + c0);
        float2 xv = *(const float2*)&x[(size_t)src * HID + c0];
        float h0 = fmaxf(a.x + pre.x + w * wr.x, 0.f);
        float h1 = fmaxf(a.y + pre.y + w * wr.y, 0.f);
        float p = h0 * w2.x + h1 * w2.y;
        #pragma unroll
        for (int m = 32; m > 0; m >>= 1) p += __shfl_xor(p, m, 64);
        float es = expf(p + b2v);
        accx = fmaf(es, xv.x, accx);
        accy = fmaf(es, xv.y, accy);
        denom += es;
    }

    float2 xt = *(const float2*)&x[(size_t)n * HID + c0];
    float inv = 1.0f / fmaxf(denom, 1e-12f);
    out[(size_t)n * HID + c0]     = xt.x + accx * inv;
    out[(size_t)n * HID + c0 + 1] = xt.y + accy * inv;
}

// ---------------- launch ----------------
extern "C" void kernel_launch(void* const* d_in, const int* in_sizes, int n_in,
                              void* d_out, int out_size, void* d_ws, size_t ws_size,
                              hipStream_t stream) {
    const float* x  = (const float*)d_in[0];
    const int*   ei = (const int*)d_in[1];
    const float* ew = (const float*)d_in[2];
    const float* W1 = (const float*)d_in[3];
    const float* b1 = (const float*)d_in[4];
    const float* W2 = (const float*)d_in[5];
    const float* b2 = (const float*)d_in[6];
    float* out = (float*)d_out;
    char* ws = (char*)d_ws;

    const size_t y_f32_bytes  = (size_t)N_NODES * 256 * sizeof(float);
    const size_t y_bf16_bytes = (size_t)N_NODES * 256 * sizeof(__hip_bfloat16);
    const size_t deg_b    = (size_t)N_NODES * 4;
    const size_t rowptr_b = (size_t)(N_NODES + 1) * 4 + 12;
    const size_t cursor_b = (size_t)N_NODES * 4;
    const size_t esrc_b   = (size_t)N_EDGES * 4;
    const size_t ewb_b    = (size_t)N_EDGES * 4;
    const size_t part_b   = (size_t)SCAN_NB * 4 * 2 + 8;
    const size_t csr_b    = deg_b + rowptr_b + cursor_b + esrc_b + ewb_b + part_b;

    const dim3 gemm_grid((N_NODES + 63) / 64, 256 / 64);
    const int edge_blocks = (N_EDGES + 255) / 256;
    const int node_wave_blocks = (N_NODES * 64 + 255) / 256;

    bool use_f32 = (ws_size >= y_f32_bytes + csr_b);
    size_t y_bytes = use_f32 ? y_f32_bytes : y_bf16_bytes;

    char* p = ws;
    void* y_ptr   = (void*)p;            p += y_bytes;
    int* deg      = (int*)p;             p += deg_b;
    int* rowptr   = (int*)p;             p += rowptr_b;
    int* cursor   = (int*)p;             p += cursor_b;
    int* esrc     = (int*)p;             p += esrc_b;
    float* ewb    = (float*)p;           p += ewb_b;
    int* partial  = (int*)p;             p += (size_t)SCAN_NB * 4;
    int* pbase    = (int*)p;

    hipMemsetAsync(deg, 0, deg_b, stream);
    hipLaunchKernelGGL(k_count, dim3(edge_blocks), dim3(256), 0, stream, ei, deg);
    hipLaunchKernelGGL(k_partial, dim3(SCAN_NB), dim3(256), 0, stream, deg, partial);
    hipLaunchKernelGGL(k_scanp, dim3(1), dim3(512), 0, stream, partial, pbase);
    hipLaunchKernelGGL(k_rowptr, dim3(SCAN_NB), dim3(256), 0, stream, deg, pbase, rowptr, cursor);
    hipLaunchKernelGGL(k_fill, dim3(edge_blocks), dim3(256), 0, stream,
                       ei, ew, cursor, esrc, ewb);

    if (use_f32) {
        float* y = (float*)y_ptr;
        hipLaunchKernelGGL(k_gemm<float>, gemm_grid, dim3(256), 0, stream, x, W1, y);
        hipLaunchKernelGGL(k_fused<float>, dim3(node_wave_blocks), dim3(256), 0, stream,
                           y, rowptr, esrc, ewb, x, W1, b1, W2, b2, out);
    } else {
        __hip_bfloat16* y = (__hip_bfloat16*)y_ptr;
        hipLaunchKernelGGL(k_gemm<__hip_bfloat16>, gemm_grid, dim3(256), 0, stream, x, W1, y);
        hipLaunchKernelGGL(k_fused<__hip_bfloat16>, dim3(node_wave_blocks), dim3(256), 0, stream,
                           y, rowptr, esrc, ewb, x, W1, b1, W2, b2, out);
    }
}

// Round 4
// 346.050 us; speedup vs baseline: 2.6064x; 1.2439x over previous
//
#include <hip/hip_runtime.h>
#include <hip/hip_bf16.h>

#define N_NODES 100000
#define N_EDGES 600000
#define HID 128
#define SCAN_NB ((N_NODES + 255) / 256)   // 391
// y row = 256 cols: [0:128) = x@W1[0:128] (src role), [128:256) = x@W1[128:256] (tgt role)

typedef short bf16x8 __attribute__((ext_vector_type(8)));
typedef float f32x4  __attribute__((ext_vector_type(4)));

// ---------------- helpers ----------------
__device__ inline float2 load2f(const float* p) { return *(const float2*)p; }
__device__ inline float2 load2f(const __hip_bfloat16* p) {
    __hip_bfloat162 v = *(const __hip_bfloat162*)p;
    return make_float2(__bfloat162float(v.x), __bfloat162float(v.y));
}
__device__ inline void store_y(float* p, float v) { *p = v; }
__device__ inline void store_y(__hip_bfloat16* p, float v) { *p = __float2bfloat16(v); }

__device__ inline unsigned short f2bf(float v) {
    __hip_bfloat16 h = __float2bfloat16(v);
    return *(unsigned short*)&h;
}
__device__ inline float bf2f(unsigned short s) {
    __hip_bfloat16 h = *(__hip_bfloat16*)&s;
    return __bfloat162float(h);
}

// ---------------- prep: W1[0:256] -> blocked bf16 hi/lo, layout [ks][n][kl] ----------------
// Bblk[(k>>5)*8192 + n*32 + (k&31)] = Wcat[k][n]
__global__ __launch_bounds__(256) void k_prepB(const float* __restrict__ W1,
                                               unsigned short* __restrict__ Bh,
                                               unsigned short* __restrict__ Bl)
{
    int idx = blockIdx.x * 256 + threadIdx.x;   // 0 .. 32767
    int n = idx & 255;
    int k = idx >> 8;                            // 0 .. 127
    float v = (n < HID) ? W1[k * HID + n] : W1[(HID + k) * HID + (n - HID)];
    unsigned short h = f2bf(v);
    float r = v - bf2f(h);
    unsigned short l = f2bf(r);
    int dst = (k >> 5) * 8192 + n * 32 + (k & 31);
    Bh[dst] = h;
    Bl[dst] = l;
}

// ---------------- K-gemm (MFMA, 3-term bf16 split): y[64 x 256] per block ----------------
template<typename YT>
__global__ __launch_bounds__(256) void k_gemm(const float* __restrict__ x,
                                              const unsigned short* __restrict__ BhG,
                                              const unsigned short* __restrict__ BlG,
                                              YT* __restrict__ y)
{
    __shared__ unsigned short Ah[64 * 32];   // [m][k] 4 KB
    __shared__ unsigned short Al[64 * 32];
    __shared__ unsigned short Bh[256 * 32];  // [n][k] 16 KB
    __shared__ unsigned short Bl[256 * 32];

    const int tid  = threadIdx.x;
    const int bm   = blockIdx.x * 64;
    const int wave = tid >> 6;
    const int lane = tid & 63;
    const int q    = lane >> 4;      // 0..3
    const int ln   = lane & 15;      // 0..15

    f32x4 acc[4][4] = {};            // [mt][nt]

    for (int ks = 0; ks < 4; ++ks) {
        const int k0 = ks * 32;
        // ---- stage A: 64 rows x 32 k, f32 -> bf16 hi/lo ----
        #pragma unroll
        for (int it = 0; it < 2; ++it) {
            int t   = tid + it * 256;      // 0..511
            int row = t >> 3;              // 0..63
            int f4  = t & 7;               // 0..7
            int gm  = bm + row;
            float4 v = make_float4(0.f, 0.f, 0.f, 0.f);
            if (gm < N_NODES) v = *(const float4*)&x[(size_t)gm * HID + k0 + f4 * 4];
            unsigned short h0 = f2bf(v.x), h1 = f2bf(v.y), h2 = f2bf(v.z), h3 = f2bf(v.w);
            unsigned int ph0 = (unsigned int)h0 | ((unsigned int)h1 << 16);
            unsigned int ph1 = (unsigned int)h2 | ((unsigned int)h3 << 16);
            unsigned short l0 = f2bf(v.x - bf2f(h0)), l1 = f2bf(v.y - bf2f(h1));
            unsigned short l2 = f2bf(v.z - bf2f(h2)), l3 = f2bf(v.w - bf2f(h3));
            unsigned int pl0 = (unsigned int)l0 | ((unsigned int)l1 << 16);
            unsigned int pl1 = (unsigned int)l2 | ((unsigned int)l3 << 16);
            int o = row * 32 + f4 * 4;
            *(uint2*)&Ah[o] = make_uint2(ph0, ph1);
            *(uint2*)&Al[o] = make_uint2(pl0, pl1);
        }
        // ---- stage B: contiguous 16 KB hi + 16 KB lo ----
        {
            const unsigned short* sh = BhG + ks * 8192;
            const unsigned short* sl = BlG + ks * 8192;
            #pragma unroll
            for (int i = 0; i < 4; ++i) {
                int o = (i * 256 + tid) * 8;
                *(uint4*)&Bh[o] = *(const uint4*)&sh[o];
                *(uint4*)&Bl[o] = *(const uint4*)&sl[o];
            }
        }
        __syncthreads();

        // ---- fragments ----
        bf16x8 ah[4], al[4], bh[4], bl[4];
        #pragma unroll
        for (int mt = 0; mt < 4; ++mt) {
            int o = (mt * 16 + ln) * 32 + q * 8;
            ah[mt] = *(const bf16x8*)&Ah[o];
            al[mt] = *(const bf16x8*)&Al[o];
        }
        #pragma unroll
        for (int nt = 0; nt < 4; ++nt) {
            int o = (wave * 64 + nt * 16 + ln) * 32 + q * 8;
            bh[nt] = *(const bf16x8*)&Bh[o];
            bl[nt] = *(const bf16x8*)&Bl[o];
        }
        #pragma unroll
        for (int mt = 0; mt < 4; ++mt) {
            #pragma unroll
            for (int nt = 0; nt < 4; ++nt) {
                acc[mt][nt] = __builtin_amdgcn_mfma_f32_16x16x32_bf16(ah[mt], bh[nt], acc[mt][nt], 0, 0, 0);
                acc[mt][nt] = __builtin_amdgcn_mfma_f32_16x16x32_bf16(ah[mt], bl[nt], acc[mt][nt], 0, 0, 0);
                acc[mt][nt] = __builtin_amdgcn_mfma_f32_16x16x32_bf16(al[mt], bh[nt], acc[mt][nt], 0, 0, 0);
            }
        }
        __syncthreads();
    }

    // ---- epilogue: C/D layout col=lane&15, row=q*4+r ----
    #pragma unroll
    for (int mt = 0; mt < 4; ++mt) {
        #pragma unroll
        for (int r = 0; r < 4; ++r) {
            int row = bm + mt * 16 + q * 4 + r;
            if (row < N_NODES) {
                #pragma unroll
                for (int nt = 0; nt < 4; ++nt) {
                    int col = wave * 64 + nt * 16 + ln;
                    store_y(&y[(size_t)row * 256 + col], acc[mt][nt][r]);
                }
            }
        }
    }
}

// ---------------- CSR build ----------------
__global__ __launch_bounds__(256) void k_count(const int* __restrict__ ei,
                                               int* __restrict__ deg)
{
    int e = blockIdx.x * blockDim.x + threadIdx.x;
    if (e < N_EDGES) atomicAdd(&deg[ei[N_EDGES + e]], 1);
}

__global__ __launch_bounds__(256) void k_partial(const int* __restrict__ deg,
                                                 int* __restrict__ partial)
{
    __shared__ int s[256];
    int t = threadIdx.x;
    int idx = blockIdx.x * 256 + t;
    s[t] = (idx < N_NODES) ? deg[idx] : 0;
    __syncthreads();
    #pragma unroll
    for (int off = 128; off > 0; off >>= 1) {
        if (t < off) s[t] += s[t + off];
        __syncthreads();
    }
    if (t == 0) partial[blockIdx.x] = s[0];
}

__global__ __launch_bounds__(512) void k_scanp(const int* __restrict__ partial,
                                               int* __restrict__ pbase)
{
    __shared__ int s[512];
    int t = threadIdx.x;
    int v = (t < SCAN_NB) ? partial[t] : 0;
    s[t] = v;
    __syncthreads();
    #pragma unroll
    for (int off = 1; off < 512; off <<= 1) {
        int u = (t >= off) ? s[t - off] : 0;
        __syncthreads();
        s[t] += u;
        __syncthreads();
    }
    if (t < SCAN_NB) pbase[t] = s[t] - v;
}

__global__ __launch_bounds__(256) void k_rowptr(const int* __restrict__ deg,
                                                const int* __restrict__ pbase,
                                                int* __restrict__ rowptr,
                                                int* __restrict__ cursor)
{
    __shared__ int s[256];
    int t = threadIdx.x;
    int b = blockIdx.x;
    int idx = b * 256 + t;
    int v = (idx < N_NODES) ? deg[idx] : 0;
    s[t] = v;
    __syncthreads();
    #pragma unroll
    for (int off = 1; off < 256; off <<= 1) {
        int u = (t >= off) ? s[t - off] : 0;
        __syncthreads();
        s[t] += u;
        __syncthreads();
    }
    if (idx < N_NODES) {
        int r = pbase[b] + s[t] - v;
        rowptr[idx] = r;
        cursor[idx] = r;
    }
    if (idx == 0) rowptr[N_NODES] = N_EDGES;
}

__global__ __launch_bounds__(256) void k_fill(const int* __restrict__ ei,
                                              const float* __restrict__ ew,
                                              int* __restrict__ cursor,
                                              int* __restrict__ esrc,
                                              float* __restrict__ ewb)
{
    int e = blockIdx.x * blockDim.x + threadIdx.x;
    if (e >= N_EDGES) return;
    int tgt = ei[N_EDGES + e];
    int pos = atomicAdd(&cursor[tgt], 1);
    esrc[pos] = ei[e];
    ewb[pos] = ew[e];
}

// ---------------- fused scores + softmax + aggregation ----------------
template<typename YT>
__global__ __launch_bounds__(256) void k_fused(const YT* __restrict__ y,
                                               const int* __restrict__ rowptr,
                                               const int* __restrict__ esrc,
                                               const float* __restrict__ ewb,
                                               const float* __restrict__ x,
                                               const float* __restrict__ W1,
                                               const float* __restrict__ b1,
                                               const float* __restrict__ W2,
                                               const float* __restrict__ b2,
                                               float* __restrict__ out)
{
    int n = (blockIdx.x * blockDim.x + threadIdx.x) >> 6;
    int lane = threadIdx.x & 63;
    if (n >= N_NODES) return;
    int c0 = lane * 2;

    float2 y2 = load2f(y + (size_t)n * 256 + 128 + c0);
    float2 bv = *(const float2*)&b1[c0];
    float2 pre = make_float2(y2.x + bv.x, y2.y + bv.y);
    float2 wr = *(const float2*)&W1[256 * HID + c0];
    float2 w2 = *(const float2*)&W2[c0];
    float b2v = b2[0];

    int beg = rowptr[n], end = rowptr[n + 1];
    float accx = 0.f, accy = 0.f, denom = 0.f;

    for (int i = beg; i < end; ++i) {
        int src = esrc[i];
        float w = ewb[i];
        float2 a  = load2f(y + (size_t)src * 256 + c0);
        float2 xv = *(const float2*)&x[(size_t)src * HID + c0];
        float h0 = fmaxf(a.x + pre.x + w * wr.x, 0.f);
        float h1 = fmaxf(a.y + pre.y + w * wr.y, 0.f);
        float p = h0 * w2.x + h1 * w2.y;
        #pragma unroll
        for (int m = 32; m > 0; m >>= 1) p += __shfl_xor(p, m, 64);
        float es = expf(p + b2v);
        accx = fmaf(es, xv.x, accx);
        accy = fmaf(es, xv.y, accy);
        denom += es;
    }

    float2 xt = *(const float2*)&x[(size_t)n * HID + c0];
    float inv = 1.0f / fmaxf(denom, 1e-12f);
    out[(size_t)n * HID + c0]     = xt.x + accx * inv;
    out[(size_t)n * HID + c0 + 1] = xt.y + accy * inv;
}

// ---------------- launch ----------------
extern "C" void kernel_launch(void* const* d_in, const int* in_sizes, int n_in,
                              void* d_out, int out_size, void* d_ws, size_t ws_size,
                              hipStream_t stream) {
    const float* x  = (const float*)d_in[0];
    const int*   ei = (const int*)d_in[1];
    const float* ew = (const float*)d_in[2];
    const float* W1 = (const float*)d_in[3];
    const float* b1 = (const float*)d_in[4];
    const float* W2 = (const float*)d_in[5];
    const float* b2 = (const float*)d_in[6];
    float* out = (float*)d_out;
    char* ws = (char*)d_ws;

    // small arrays first (all sizes 16B multiples), y last
    const size_t deg_b    = 400000;                  // N_NODES*4
    const size_t rowptr_b = 400016;                  // (N_NODES+1)*4 padded
    const size_t cursor_b = 400000;
    const size_t esrc_b   = 2400000;                 // N_EDGES*4
    const size_t ewb_b    = 2400000;
    const size_t part_b   = 1568;                    // SCAN_NB*4 padded
    const size_t pb_b     = 1568;
    const size_t Bh_b     = 65536;                   // 128*256 bf16
    const size_t Bl_b     = 65536;
    const size_t small_b  = deg_b + rowptr_b + cursor_b + esrc_b + ewb_b + part_b + pb_b + Bh_b + Bl_b;

    const size_t y_f32_bytes  = (size_t)N_NODES * 256 * sizeof(float);

    char* p = ws;
    int* deg      = (int*)p;             p += deg_b;
    int* rowptr   = (int*)p;             p += rowptr_b;
    int* cursor   = (int*)p;             p += cursor_b;
    int* esrc     = (int*)p;             p += esrc_b;
    float* ewb    = (float*)p;           p += ewb_b;
    int* partial  = (int*)p;             p += part_b;
    int* pbase    = (int*)p;             p += pb_b;
    unsigned short* BhG = (unsigned short*)p;  p += Bh_b;
    unsigned short* BlG = (unsigned short*)p;  p += Bl_b;
    void* y_ptr   = (void*)p;

    const int edge_blocks = (N_EDGES + 255) / 256;
    const int node_wave_blocks = (N_NODES * 64 + 255) / 256;
    const int gemm_blocks = (N_NODES + 63) / 64;     // 1563

    bool use_f32 = (ws_size >= small_b + y_f32_bytes);

    hipMemsetAsync(deg, 0, deg_b, stream);
    hipLaunchKernelGGL(k_prepB, dim3(128), dim3(256), 0, stream, W1, BhG, BlG);
    hipLaunchKernelGGL(k_count, dim3(edge_blocks), dim3(256), 0, stream, ei, deg);
    hipLaunchKernelGGL(k_partial, dim3(SCAN_NB), dim3(256), 0, stream, deg, partial);
    hipLaunchKernelGGL(k_scanp, dim3(1), dim3(512), 0, stream, partial, pbase);
    hipLaunchKernelGGL(k_rowptr, dim3(SCAN_NB), dim3(256), 0, stream, deg, pbase, rowptr, cursor);
    hipLaunchKernelGGL(k_fill, dim3(edge_blocks), dim3(256), 0, stream,
                       ei, ew, cursor, esrc, ewb);

    if (use_f32) {
        float* y = (float*)y_ptr;
        hipLaunchKernelGGL(k_gemm<float>, dim3(gemm_blocks), dim3(256), 0, stream, x, BhG, BlG, y);
        hipLaunchKernelGGL(k_fused<float>, dim3(node_wave_blocks), dim3(256), 0, stream,
                           y, rowptr, esrc, ewb, x, W1, b1, W2, b2, out);
    } else {
        __hip_bfloat16* y = (__hip_bfloat16*)y_ptr;
        hipLaunchKernelGGL(k_gemm<__hip_bfloat16>, dim3(gemm_blocks), dim3(256), 0, stream, x, BhG, BlG, y);
        hipLaunchKernelGGL(k_fused<__hip_bfloat16>, dim3(node_wave_blocks), dim3(256), 0, stream,
                           y, rowptr, esrc, ewb, x, W1, b1, W2, b2, out);
    }
}

// Round 5
// 301.020 us; speedup vs baseline: 2.9963x; 1.1496x over previous
//
#include <hip/hip_runtime.h>
#include <hip/hip_bf16.h>

#define N_NODES 100000
#define N_EDGES 600000
#define HID 128
#define SCAN_NB ((N_NODES + 255) / 256)   // 391

// zbuf[n] = 256 bf16: [0:128) y1 = x@W1[0:128] (gathered, src role), [128:256) xbf = bf16(x[n])
// y2buf[n] = 128 bf16: x@W1[128:256] (sequential, tgt role)

typedef short bf16x8 __attribute__((ext_vector_type(8)));
typedef float f32x4  __attribute__((ext_vector_type(4)));

// ---------------- helpers ----------------
__device__ inline unsigned short f2bf(float v) {
    __hip_bfloat16 h = __float2bfloat16(v);
    return *(unsigned short*)&h;
}
__device__ inline float bf2f(unsigned short s) {
    unsigned int u = (unsigned int)s << 16;
    return __uint_as_float(u);
}
// packed pair of bf16 (little-endian: low half = first element) -> float2
__device__ inline float2 bfpair(unsigned int u) {
    float lo = __uint_as_float(u << 16);
    float hi = __uint_as_float(u & 0xffff0000u);
    return make_float2(lo, hi);
}

// ---------------- prep: W1[0:256] -> blocked bf16 hi/lo, layout [ks][n][kl] ----------------
__global__ __launch_bounds__(256) void k_prepB(const float* __restrict__ W1,
                                               unsigned short* __restrict__ Bh,
                                               unsigned short* __restrict__ Bl)
{
    int idx = blockIdx.x * 256 + threadIdx.x;   // 0 .. 32767
    int n = idx & 255;
    int k = idx >> 8;                            // 0 .. 127
    float v = (n < HID) ? W1[k * HID + n] : W1[(HID + k) * HID + (n - HID)];
    unsigned short h = f2bf(v);
    float r = v - bf2f(h);
    unsigned short l = f2bf(r);
    int dst = (k >> 5) * 8192 + n * 32 + (k & 31);
    Bh[dst] = h;
    Bl[dst] = l;
}

// ---------------- K-gemm (MFMA, 3-term bf16 split) ----------------
// block = 64 rows x 256 cols; B fragments straight from global (L2-hot 128 KB)
__global__ __launch_bounds__(256) void k_gemm(const float* __restrict__ x,
                                              const unsigned short* __restrict__ BhG,
                                              const unsigned short* __restrict__ BlG,
                                              unsigned short* __restrict__ zbuf,
                                              unsigned short* __restrict__ y2buf)
{
    __shared__ unsigned short Ah[64 * 32];   // [m][k] 4 KB
    __shared__ unsigned short Al[64 * 32];

    const int tid  = threadIdx.x;
    const int bm   = blockIdx.x * 64;
    const int wave = tid >> 6;
    const int lane = tid & 63;
    const int q    = lane >> 4;      // 0..3
    const int ln   = lane & 15;      // 0..15

    f32x4 acc[4][4] = {};            // [mt][nt]

    for (int ks = 0; ks < 4; ++ks) {
        const int k0 = ks * 32;
        // ---- stage A: 64 rows x 32 k, f32 -> bf16 hi/lo; also emit xbf to zbuf ----
        #pragma unroll
        for (int it = 0; it < 2; ++it) {
            int t   = tid + it * 256;      // 0..511
            int row = t >> 3;              // 0..63
            int f4  = t & 7;               // 0..7
            int gm  = bm + row;
            float4 v = make_float4(0.f, 0.f, 0.f, 0.f);
            if (gm < N_NODES) v = *(const float4*)&x[(size_t)gm * HID + k0 + f4 * 4];
            unsigned short h0 = f2bf(v.x), h1 = f2bf(v.y), h2 = f2bf(v.z), h3 = f2bf(v.w);
            unsigned int ph0 = (unsigned int)h0 | ((unsigned int)h1 << 16);
            unsigned int ph1 = (unsigned int)h2 | ((unsigned int)h3 << 16);
            unsigned short l0 = f2bf(v.x - bf2f(h0)), l1 = f2bf(v.y - bf2f(h1));
            unsigned short l2 = f2bf(v.z - bf2f(h2)), l3 = f2bf(v.w - bf2f(h3));
            unsigned int pl0 = (unsigned int)l0 | ((unsigned int)l1 << 16);
            unsigned int pl1 = (unsigned int)l2 | ((unsigned int)l3 << 16);
            int o = row * 32 + f4 * 4;
            *(uint2*)&Ah[o] = make_uint2(ph0, ph1);
            *(uint2*)&Al[o] = make_uint2(pl0, pl1);
            if (gm < N_NODES) {
                // xbf half of zbuf: cols 128 + k0 + f4*4 .. +3
                *(uint2*)&zbuf[(size_t)gm * 256 + 128 + k0 + f4 * 4] = make_uint2(ph0, ph1);
            }
        }
        __syncthreads();

        // ---- fragments ----
        bf16x8 ah[4], al[4], bh[4], bl[4];
        #pragma unroll
        for (int mt = 0; mt < 4; ++mt) {
            int o = (mt * 16 + ln) * 32 + q * 8;
            ah[mt] = *(const bf16x8*)&Ah[o];
            al[mt] = *(const bf16x8*)&Al[o];
        }
        #pragma unroll
        for (int nt = 0; nt < 4; ++nt) {
            int o = ks * 8192 + (wave * 64 + nt * 16 + ln) * 32 + q * 8;
            bh[nt] = *(const bf16x8*)&BhG[o];
            bl[nt] = *(const bf16x8*)&BlG[o];
        }
        #pragma unroll
        for (int mt = 0; mt < 4; ++mt) {
            #pragma unroll
            for (int nt = 0; nt < 4; ++nt) {
                acc[mt][nt] = __builtin_amdgcn_mfma_f32_16x16x32_bf16(ah[mt], bh[nt], acc[mt][nt], 0, 0, 0);
                acc[mt][nt] = __builtin_amdgcn_mfma_f32_16x16x32_bf16(ah[mt], bl[nt], acc[mt][nt], 0, 0, 0);
                acc[mt][nt] = __builtin_amdgcn_mfma_f32_16x16x32_bf16(al[mt], bh[nt], acc[mt][nt], 0, 0, 0);
            }
        }
        __syncthreads();
    }

    // ---- epilogue: C/D layout col=ln, row=q*4+r; waves 0,1 -> y1 (zbuf), waves 2,3 -> y2buf ----
    #pragma unroll
    for (int mt = 0; mt < 4; ++mt) {
        #pragma unroll
        for (int r = 0; r < 4; ++r) {
            int row = bm + mt * 16 + q * 4 + r;
            if (row < N_NODES) {
                #pragma unroll
                for (int nt = 0; nt < 4; ++nt) {
                    int col = wave * 64 + nt * 16 + ln;
                    unsigned short v = f2bf(acc[mt][nt][r]);
                    if (col < 128) zbuf[(size_t)row * 256 + col] = v;
                    else           y2buf[(size_t)row * 128 + (col - 128)] = v;
                }
            }
        }
    }
}

// ---------------- CSR build ----------------
__global__ __launch_bounds__(256) void k_count(const int* __restrict__ ei,
                                               int* __restrict__ deg)
{
    int e = blockIdx.x * blockDim.x + threadIdx.x;
    if (e < N_EDGES) atomicAdd(&deg[ei[N_EDGES + e]], 1);
}

__global__ __launch_bounds__(256) void k_partial(const int* __restrict__ deg,
                                                 int* __restrict__ partial)
{
    __shared__ int s[256];
    int t = threadIdx.x;
    int idx = blockIdx.x * 256 + t;
    s[t] = (idx < N_NODES) ? deg[idx] : 0;
    __syncthreads();
    #pragma unroll
    for (int off = 128; off > 0; off >>= 1) {
        if (t < off) s[t] += s[t + off];
        __syncthreads();
    }
    if (t == 0) partial[blockIdx.x] = s[0];
}

__global__ __launch_bounds__(512) void k_scanp(const int* __restrict__ partial,
                                               int* __restrict__ pbase)
{
    __shared__ int s[512];
    int t = threadIdx.x;
    int v = (t < SCAN_NB) ? partial[t] : 0;
    s[t] = v;
    __syncthreads();
    #pragma unroll
    for (int off = 1; off < 512; off <<= 1) {
        int u = (t >= off) ? s[t - off] : 0;
        __syncthreads();
        s[t] += u;
        __syncthreads();
    }
    if (t < SCAN_NB) pbase[t] = s[t] - v;
}

__global__ __launch_bounds__(256) void k_rowptr(const int* __restrict__ deg,
                                                const int* __restrict__ pbase,
                                                int* __restrict__ rowptr,
                                                int* __restrict__ cursor)
{
    __shared__ int s[256];
    int t = threadIdx.x;
    int b = blockIdx.x;
    int idx = b * 256 + t;
    int v = (idx < N_NODES) ? deg[idx] : 0;
    s[t] = v;
    __syncthreads();
    #pragma unroll
    for (int off = 1; off < 256; off <<= 1) {
        int u = (t >= off) ? s[t - off] : 0;
        __syncthreads();
        s[t] += u;
        __syncthreads();
    }
    if (idx < N_NODES) {
        int r = pbase[b] + s[t] - v;
        rowptr[idx] = r;
        cursor[idx] = r;
    }
    if (idx == 0) rowptr[N_NODES] = N_EDGES;
}

__global__ __launch_bounds__(256) void k_fill(const int* __restrict__ ei,
                                              const float* __restrict__ ew,
                                              int* __restrict__ cursor,
                                              int* __restrict__ esrc,
                                              float* __restrict__ ewb)
{
    int e = blockIdx.x * blockDim.x + threadIdx.x;
    if (e >= N_EDGES) return;
    int tgt = ei[N_EDGES + e];
    int pos = atomicAdd(&cursor[tgt], 1);
    esrc[pos] = ei[e];
    ewb[pos] = ew[e];
}

// ---------------- fused scores + softmax + aggregation ----------------
// one wave per node; lane handles cols 2*lane, 2*lane+1; 2-edge ILP unroll
__global__ __launch_bounds__(256) void k_fused(const unsigned int* __restrict__ zu,   // zbuf as uint
                                               const unsigned int* __restrict__ y2u,  // y2buf as uint
                                               const int* __restrict__ rowptr,
                                               const int* __restrict__ esrc,
                                               const float* __restrict__ ewb,
                                               const float* __restrict__ x,
                                               const float* __restrict__ W1,
                                               const float* __restrict__ b1,
                                               const float* __restrict__ W2,
                                               const float* __restrict__ b2,
                                               float* __restrict__ out)
{
    int n = (blockIdx.x * blockDim.x + threadIdx.x) >> 6;
    int lane = threadIdx.x & 63;
    if (n >= N_NODES) return;
    int c0 = lane * 2;

    float2 y2 = bfpair(y2u[(size_t)n * 64 + lane]);
    float2 bv = *(const float2*)&b1[c0];
    float2 pre = make_float2(y2.x + bv.x, y2.y + bv.y);
    float2 wr = *(const float2*)&W1[256 * HID + c0];
    float2 w2 = *(const float2*)&W2[c0];
    float b2v = b2[0];

    int beg = rowptr[n], end = rowptr[n + 1];
    float accx = 0.f, accy = 0.f, denom = 0.f;

    int i = beg;
    for (; i + 2 <= end; i += 2) {
        int src0 = esrc[i],     src1 = esrc[i + 1];
        float w0 = ewb[i],      w1 = ewb[i + 1];
        unsigned int ua0 = zu[(size_t)src0 * 128 + lane];
        unsigned int ux0 = zu[(size_t)src0 * 128 + 64 + lane];
        unsigned int ua1 = zu[(size_t)src1 * 128 + lane];
        unsigned int ux1 = zu[(size_t)src1 * 128 + 64 + lane];
        float2 a0 = bfpair(ua0), a1 = bfpair(ua1);
        float h00 = fmaxf(a0.x + pre.x + w0 * wr.x, 0.f);
        float h01 = fmaxf(a0.y + pre.y + w0 * wr.y, 0.f);
        float h10 = fmaxf(a1.x + pre.x + w1 * wr.x, 0.f);
        float h11 = fmaxf(a1.y + pre.y + w1 * wr.y, 0.f);
        float p0 = h00 * w2.x + h01 * w2.y;
        float p1 = h10 * w2.x + h11 * w2.y;
        #pragma unroll
        for (int m = 32; m > 0; m >>= 1) {
            p0 += __shfl_xor(p0, m, 64);
            p1 += __shfl_xor(p1, m, 64);
        }
        float es0 = __expf(p0 + b2v);
        float es1 = __expf(p1 + b2v);
        float2 xf0 = bfpair(ux0), xf1 = bfpair(ux1);
        accx = fmaf(es0, xf0.x, accx); accy = fmaf(es0, xf0.y, accy);
        accx = fmaf(es1, xf1.x, accx); accy = fmaf(es1, xf1.y, accy);
        denom += es0 + es1;
    }
    if (i < end) {
        int src0 = esrc[i];
        float w0 = ewb[i];
        unsigned int ua0 = zu[(size_t)src0 * 128 + lane];
        unsigned int ux0 = zu[(size_t)src0 * 128 + 64 + lane];
        float2 a0 = bfpair(ua0);
        float h00 = fmaxf(a0.x + pre.x + w0 * wr.x, 0.f);
        float h01 = fmaxf(a0.y + pre.y + w0 * wr.y, 0.f);
        float p0 = h00 * w2.x + h01 * w2.y;
        #pragma unroll
        for (int m = 32; m > 0; m >>= 1) p0 += __shfl_xor(p0, m, 64);
        float es0 = __expf(p0 + b2v);
        float2 xf0 = bfpair(ux0);
        accx = fmaf(es0, xf0.x, accx); accy = fmaf(es0, xf0.y, accy);
        denom += es0;
    }

    float2 xt = *(const float2*)&x[(size_t)n * HID + c0];
    float inv = 1.0f / fmaxf(denom, 1e-12f);
    out[(size_t)n * HID + c0]     = xt.x + accx * inv;
    out[(size_t)n * HID + c0 + 1] = xt.y + accy * inv;
}

// ---------------- launch ----------------
extern "C" void kernel_launch(void* const* d_in, const int* in_sizes, int n_in,
                              void* d_out, int out_size, void* d_ws, size_t ws_size,
                              hipStream_t stream) {
    const float* x  = (const float*)d_in[0];
    const int*   ei = (const int*)d_in[1];
    const float* ew = (const float*)d_in[2];
    const float* W1 = (const float*)d_in[3];
    const float* b1 = (const float*)d_in[4];
    const float* W2 = (const float*)d_in[5];
    const float* b2 = (const float*)d_in[6];
    float* out = (float*)d_out;
    char* ws = (char*)d_ws;

    const size_t deg_b    = 400000;
    const size_t rowptr_b = 400016;
    const size_t cursor_b = 400000;
    const size_t esrc_b   = 2400000;
    const size_t ewb_b    = 2400000;
    const size_t part_b   = 1568;
    const size_t pb_b     = 1568;
    const size_t Bh_b     = 65536;
    const size_t Bl_b     = 65536;

    char* p = ws;
    int* deg      = (int*)p;             p += deg_b;
    int* rowptr   = (int*)p;             p += rowptr_b;
    int* cursor   = (int*)p;             p += cursor_b;
    int* esrc     = (int*)p;             p += esrc_b;
    float* ewb    = (float*)p;           p += ewb_b;
    int* partial  = (int*)p;             p += part_b;
    int* pbase    = (int*)p;             p += pb_b;
    unsigned short* BhG = (unsigned short*)p;  p += Bh_b;
    unsigned short* BlG = (unsigned short*)p;  p += Bl_b;
    unsigned short* zbuf  = (unsigned short*)p;  p += (size_t)N_NODES * 256 * 2;  // 51.2 MB
    unsigned short* y2buf = (unsigned short*)p;                                   // 25.6 MB

    const int edge_blocks = (N_EDGES + 255) / 256;
    const int node_wave_blocks = (N_NODES * 64 + 255) / 256;
    const int gemm_blocks = (N_NODES + 63) / 64;     // 1563

    hipMemsetAsync(deg, 0, deg_b, stream);
    hipLaunchKernelGGL(k_prepB, dim3(128), dim3(256), 0, stream, W1, BhG, BlG);
    hipLaunchKernelGGL(k_count, dim3(edge_blocks), dim3(256), 0, stream, ei, deg);
    hipLaunchKernelGGL(k_partial, dim3(SCAN_NB), dim3(256), 0, stream, deg, partial);
    hipLaunchKernelGGL(k_scanp, dim3(1), dim3(512), 0, stream, partial, pbase);
    hipLaunchKernelGGL(k_rowptr, dim3(SCAN_NB), dim3(256), 0, stream, deg, pbase, rowptr, cursor);
    hipLaunchKernelGGL(k_fill, dim3(edge_blocks), dim3(256), 0, stream,
                       ei, ew, cursor, esrc, ewb);
    hipLaunchKernelGGL(k_gemm, dim3(gemm_blocks), dim3(256), 0, stream, x, BhG, BlG, zbuf, y2buf);
    hipLaunchKernelGGL(k_fused, dim3(node_wave_blocks), dim3(256), 0, stream,
                       (const unsigned int*)zbuf, (const unsigned int*)y2buf,
                       rowptr, esrc, ewb, x, W1, b1, W2, b2, out);
}

// Round 6
// 288.390 us; speedup vs baseline: 3.1275x; 1.0438x over previous
//
#include <hip/hip_runtime.h>
#include <hip/hip_bf16.h>

#define N_NODES 100000
#define N_EDGES 600000
#define HID 128
#define SCAN_NB ((N_NODES + 255) / 256)   // 391

// zbuf[n] = 256 bf16: [0:128) y1 = x@W1[0:128] (gathered, src role), [128:256) xbf = bf16(x[n])
// y2buf[n] = 128 bf16: x@W1[128:256] (sequential, tgt role)
// eprs[pos] = (uint src, float-bits w) in CSR-by-target order

typedef short bf16x8 __attribute__((ext_vector_type(8)));
typedef float f32x4  __attribute__((ext_vector_type(4)));

// ---------------- helpers ----------------
__device__ inline unsigned short f2bf(float v) {
    __hip_bfloat16 h = __float2bfloat16(v);
    return *(unsigned short*)&h;
}
__device__ inline float bf2f(unsigned short s) {
    unsigned int u = (unsigned int)s << 16;
    return __uint_as_float(u);
}
// packed pair of bf16 -> float2 (low half = first element)
__device__ inline float2 bfpair(unsigned int u) {
    float lo = __uint_as_float(u << 16);
    float hi = __uint_as_float(u & 0xffff0000u);
    return make_float2(lo, hi);
}

// ---------------- prep: zero deg + W1[0:256] -> blocked bf16 hi/lo [ks][n][kl] ----------------
__global__ __launch_bounds__(256) void k_prep(const float* __restrict__ W1,
                                              unsigned short* __restrict__ Bh,
                                              unsigned short* __restrict__ Bl,
                                              int* __restrict__ deg)
{
    int idx = blockIdx.x * 256 + threadIdx.x;
    if (idx < N_NODES) deg[idx] = 0;
    if (idx < 32768) {
        int n = idx & 255;
        int k = idx >> 8;                            // 0 .. 127
        float v = (n < HID) ? W1[k * HID + n] : W1[(HID + k) * HID + (n - HID)];
        unsigned short h = f2bf(v);
        float r = v - bf2f(h);
        unsigned short l = f2bf(r);
        int dst = (k >> 5) * 8192 + n * 32 + (k & 31);
        Bh[dst] = h;
        Bl[dst] = l;
    }
}

// ---------------- K-gemm (MFMA, 3-term bf16 split, x-prefetch) ----------------
__global__ __launch_bounds__(256) void k_gemm(const float* __restrict__ x,
                                              const unsigned short* __restrict__ BhG,
                                              const unsigned short* __restrict__ BlG,
                                              unsigned short* __restrict__ zbuf,
                                              unsigned short* __restrict__ y2buf)
{
    __shared__ unsigned short Ah[64 * 32];   // [m][k] 4 KB
    __shared__ unsigned short Al[64 * 32];

    const int tid  = threadIdx.x;
    const int bm   = blockIdx.x * 64;
    const int wave = tid >> 6;
    const int lane = tid & 63;
    const int q    = lane >> 4;      // 0..3
    const int ln   = lane & 15;      // 0..15

    // stage-A decode: this thread handles (rowA,f4) and (rowB,f4)
    const int rowA = tid >> 3;              // 0..31
    const int rowB = rowA + 32;             // 32..63
    const int f4   = tid & 7;               // 0..7
    const int gmA  = bm + rowA;
    const int gmB  = bm + rowB;
    const bool okA = gmA < N_NODES;
    const bool okB = gmB < N_NODES;
    const float* pxA = &x[(size_t)gmA * HID + f4 * 4];
    const float* pxB = &x[(size_t)gmB * HID + f4 * 4];

    f32x4 acc[4][4] = {};            // [mt][nt]

    float4 vA = make_float4(0.f,0.f,0.f,0.f), vB = vA;
    float4 vAn = vA, vBn = vA;
    if (okA) vA = *(const float4*)pxA;
    if (okB) vB = *(const float4*)pxB;

    for (int ks = 0; ks < 4; ++ks) {
        const int k0 = ks * 32;
        // ---- stage A: convert current chunk, store LDS + xbf half of zbuf ----
        {
            float4 v = vA;
            unsigned short h0 = f2bf(v.x), h1 = f2bf(v.y), h2 = f2bf(v.z), h3 = f2bf(v.w);
            unsigned int ph0 = (unsigned int)h0 | ((unsigned int)h1 << 16);
            unsigned int ph1 = (unsigned int)h2 | ((unsigned int)h3 << 16);
            unsigned short l0 = f2bf(v.x - bf2f(h0)), l1 = f2bf(v.y - bf2f(h1));
            unsigned short l2 = f2bf(v.z - bf2f(h2)), l3 = f2bf(v.w - bf2f(h3));
            unsigned int pl0 = (unsigned int)l0 | ((unsigned int)l1 << 16);
            unsigned int pl1 = (unsigned int)l2 | ((unsigned int)l3 << 16);
            int o = rowA * 32 + f4 * 4;
            *(uint2*)&Ah[o] = make_uint2(ph0, ph1);
            *(uint2*)&Al[o] = make_uint2(pl0, pl1);
            if (okA) *(uint2*)&zbuf[(size_t)gmA * 256 + 128 + k0 + f4 * 4] = make_uint2(ph0, ph1);
        }
        {
            float4 v = vB;
            unsigned short h0 = f2bf(v.x), h1 = f2bf(v.y), h2 = f2bf(v.z), h3 = f2bf(v.w);
            unsigned int ph0 = (unsigned int)h0 | ((unsigned int)h1 << 16);
            unsigned int ph1 = (unsigned int)h2 | ((unsigned int)h3 << 16);
            unsigned short l0 = f2bf(v.x - bf2f(h0)), l1 = f2bf(v.y - bf2f(h1));
            unsigned short l2 = f2bf(v.z - bf2f(h2)), l3 = f2bf(v.w - bf2f(h3));
            unsigned int pl0 = (unsigned int)l0 | ((unsigned int)l1 << 16);
            unsigned int pl1 = (unsigned int)l2 | ((unsigned int)l3 << 16);
            int o = rowB * 32 + f4 * 4;
            *(uint2*)&Ah[o] = make_uint2(ph0, ph1);
            *(uint2*)&Al[o] = make_uint2(pl0, pl1);
            if (okB) *(uint2*)&zbuf[(size_t)gmB * 256 + 128 + k0 + f4 * 4] = make_uint2(ph0, ph1);
        }
        __syncthreads();

        // ---- prefetch next chunk's x (hidden behind ds_read + MFMA) ----
        if (ks < 3) {
            vAn = okA ? *(const float4*)(pxA + (ks + 1) * 32) : make_float4(0.f,0.f,0.f,0.f);
            vBn = okB ? *(const float4*)(pxB + (ks + 1) * 32) : make_float4(0.f,0.f,0.f,0.f);
        }

        // ---- fragments ----
        bf16x8 ah[4], al[4], bh[4], bl[4];
        #pragma unroll
        for (int mt = 0; mt < 4; ++mt) {
            int o = (mt * 16 + ln) * 32 + q * 8;
            ah[mt] = *(const bf16x8*)&Ah[o];
            al[mt] = *(const bf16x8*)&Al[o];
        }
        #pragma unroll
        for (int nt = 0; nt < 4; ++nt) {
            int o = ks * 8192 + (wave * 64 + nt * 16 + ln) * 32 + q * 8;
            bh[nt] = *(const bf16x8*)&BhG[o];
            bl[nt] = *(const bf16x8*)&BlG[o];
        }
        #pragma unroll
        for (int mt = 0; mt < 4; ++mt) {
            #pragma unroll
            for (int nt = 0; nt < 4; ++nt) {
                acc[mt][nt] = __builtin_amdgcn_mfma_f32_16x16x32_bf16(ah[mt], bh[nt], acc[mt][nt], 0, 0, 0);
                acc[mt][nt] = __builtin_amdgcn_mfma_f32_16x16x32_bf16(ah[mt], bl[nt], acc[mt][nt], 0, 0, 0);
                acc[mt][nt] = __builtin_amdgcn_mfma_f32_16x16x32_bf16(al[mt], bh[nt], acc[mt][nt], 0, 0, 0);
            }
        }
        __syncthreads();
        vA = vAn; vB = vBn;
    }

    // ---- epilogue: C/D layout col=ln, row=q*4+r; waves 0,1 -> y1 (zbuf), waves 2,3 -> y2buf ----
    #pragma unroll
    for (int mt = 0; mt < 4; ++mt) {
        #pragma unroll
        for (int r = 0; r < 4; ++r) {
            int row = bm + mt * 16 + q * 4 + r;
            if (row < N_NODES) {
                #pragma unroll
                for (int nt = 0; nt < 4; ++nt) {
                    int col = wave * 64 + nt * 16 + ln;
                    unsigned short v = f2bf(acc[mt][nt][r]);
                    if (col < 128) zbuf[(size_t)row * 256 + col] = v;
                    else           y2buf[(size_t)row * 128 + (col - 128)] = v;
                }
            }
        }
    }
}

// ---------------- CSR build ----------------
__global__ __launch_bounds__(256) void k_count(const int* __restrict__ ei,
                                               int* __restrict__ deg)
{
    int e = blockIdx.x * blockDim.x + threadIdx.x;
    if (e < N_EDGES) atomicAdd(&deg[ei[N_EDGES + e]], 1);
}

__global__ __launch_bounds__(256) void k_partial(const int* __restrict__ deg,
                                                 int* __restrict__ partial)
{
    __shared__ int s[256];
    int t = threadIdx.x;
    int idx = blockIdx.x * 256 + t;
    s[t] = (idx < N_NODES) ? deg[idx] : 0;
    __syncthreads();
    #pragma unroll
    for (int off = 128; off > 0; off >>= 1) {
        if (t < off) s[t] += s[t + off];
        __syncthreads();
    }
    if (t == 0) partial[blockIdx.x] = s[0];
}

__global__ __launch_bounds__(512) void k_scanp(const int* __restrict__ partial,
                                               int* __restrict__ pbase)
{
    __shared__ int s[512];
    int t = threadIdx.x;
    int v = (t < SCAN_NB) ? partial[t] : 0;
    s[t] = v;
    __syncthreads();
    #pragma unroll
    for (int off = 1; off < 512; off <<= 1) {
        int u = (t >= off) ? s[t - off] : 0;
        __syncthreads();
        s[t] += u;
        __syncthreads();
    }
    if (t < SCAN_NB) pbase[t] = s[t] - v;
}

__global__ __launch_bounds__(256) void k_rowptr(const int* __restrict__ deg,
                                                const int* __restrict__ pbase,
                                                int* __restrict__ rowptr,
                                                int* __restrict__ cursor)
{
    __shared__ int s[256];
    int t = threadIdx.x;
    int b = blockIdx.x;
    int idx = b * 256 + t;
    int v = (idx < N_NODES) ? deg[idx] : 0;
    s[t] = v;
    __syncthreads();
    #pragma unroll
    for (int off = 1; off < 256; off <<= 1) {
        int u = (t >= off) ? s[t - off] : 0;
        __syncthreads();
        s[t] += u;
        __syncthreads();
    }
    if (idx < N_NODES) {
        int r = pbase[b] + s[t] - v;
        rowptr[idx] = r;
        cursor[idx] = r;
    }
    if (idx == 0) rowptr[N_NODES] = N_EDGES;
}

__global__ __launch_bounds__(256) void k_fill(const int* __restrict__ ei,
                                              const float* __restrict__ ew,
                                              int* __restrict__ cursor,
                                              uint2* __restrict__ eprs)
{
    int e = blockIdx.x * blockDim.x + threadIdx.x;
    if (e >= N_EDGES) return;
    int tgt = ei[N_EDGES + e];
    int pos = atomicAdd(&cursor[tgt], 1);
    eprs[pos] = make_uint2((unsigned int)ei[e], __float_as_uint(ew[e]));
}

// ---------------- fused scores + softmax + aggregation ----------------
// one wave per node; half-wave per edge (lanes 0-31: edge i, 32-63: edge i+1);
// lane holds 4 cols; ILP-2 over edge pairs (4 edges per iteration)
__global__ __launch_bounds__(256) void k_fused(const unsigned int* __restrict__ zu,
                                               const unsigned int* __restrict__ y2u,
                                               const int* __restrict__ rowptr,
                                               const uint2* __restrict__ eprs,
                                               const float* __restrict__ x,
                                               const float* __restrict__ W1,
                                               const float* __restrict__ b1,
                                               const float* __restrict__ W2,
                                               const float* __restrict__ b2,
                                               float* __restrict__ out)
{
    int n = (blockIdx.x * blockDim.x + threadIdx.x) >> 6;
    int lane = threadIdx.x & 63;
    if (n >= N_NODES) return;
    int sl = lane & 31;
    int hl = lane >> 5;
    int c0 = sl * 4;

    // per-lane constants for 4 cols (same for both halves)
    uint2 uy2 = *(const uint2*)&y2u[(size_t)n * 64 + sl * 2];
    float2 y2a = bfpair(uy2.x), y2b = bfpair(uy2.y);
    float4 bv = *(const float4*)&b1[c0];
    float4 wr = *(const float4*)&W1[256 * HID + c0];
    float4 w2 = *(const float4*)&W2[c0];
    float pc0 = y2a.x + bv.x, pc1 = y2a.y + bv.y;
    float pc2 = y2b.x + bv.z, pc3 = y2b.y + bv.w;
    float b2v = b2[0];

    int beg = rowptr[n], end = rowptr[n + 1];
    float acc0 = 0.f, acc1 = 0.f, acc2 = 0.f, acc3 = 0.f, denom = 0.f;

    for (int i = beg; i < end; i += 4) {
        int idxA = i + hl;
        int idxB = i + 2 + hl;
        bool vA = idxA < end;
        bool vB = idxB < end;
        int iA = vA ? idxA : (end - 1);
        int iB = vB ? idxB : (end - 1);
        uint2 epA = eprs[iA];
        uint2 epB = eprs[iB];
        size_t bA = (size_t)epA.x * 128;
        size_t bB = (size_t)epB.x * 128;
        float wA = __uint_as_float(epA.y);
        float wB = __uint_as_float(epB.y);
        uint2 uyA = *(const uint2*)&zu[bA + sl * 2];
        uint2 uxA = *(const uint2*)&zu[bA + 64 + sl * 2];
        uint2 uyB = *(const uint2*)&zu[bB + sl * 2];
        uint2 uxB = *(const uint2*)&zu[bB + 64 + sl * 2];

        float2 aA0 = bfpair(uyA.x), aA1 = bfpair(uyA.y);
        float hA0 = fmaxf(fmaf(wA, wr.x, aA0.x + pc0), 0.f);
        float hA1 = fmaxf(fmaf(wA, wr.y, aA0.y + pc1), 0.f);
        float hA2 = fmaxf(fmaf(wA, wr.z, aA1.x + pc2), 0.f);
        float hA3 = fmaxf(fmaf(wA, wr.w, aA1.y + pc3), 0.f);
        float pA = hA0 * w2.x + hA1 * w2.y + hA2 * w2.z + hA3 * w2.w;

        float2 aB0 = bfpair(uyB.x), aB1 = bfpair(uyB.y);
        float hB0 = fmaxf(fmaf(wB, wr.x, aB0.x + pc0), 0.f);
        float hB1 = fmaxf(fmaf(wB, wr.y, aB0.y + pc1), 0.f);
        float hB2 = fmaxf(fmaf(wB, wr.z, aB1.x + pc2), 0.f);
        float hB3 = fmaxf(fmaf(wB, wr.w, aB1.y + pc3), 0.f);
        float pB = hB0 * w2.x + hB1 * w2.y + hB2 * w2.z + hB3 * w2.w;

        // reduce within each 32-lane half (xor masks <= 16 stay in-half)
        #pragma unroll
        for (int m = 1; m <= 16; m <<= 1) {
            pA += __shfl_xor(pA, m, 64);
            pB += __shfl_xor(pB, m, 64);
        }
        float esA = __expf(pA + b2v); if (!vA) esA = 0.f;
        float esB = __expf(pB + b2v); if (!vB) esB = 0.f;

        float2 xA0 = bfpair(uxA.x), xA1 = bfpair(uxA.y);
        float2 xB0 = bfpair(uxB.x), xB1 = bfpair(uxB.y);
        acc0 = fmaf(esA, xA0.x, acc0); acc0 = fmaf(esB, xB0.x, acc0);
        acc1 = fmaf(esA, xA0.y, acc1); acc1 = fmaf(esB, xB0.y, acc1);
        acc2 = fmaf(esA, xA1.x, acc2); acc2 = fmaf(esB, xB1.x, acc2);
        acc3 = fmaf(esA, xA1.y, acc3); acc3 = fmaf(esB, xB1.y, acc3);
        denom += esA + esB;
    }

    // merge halves
    acc0 += __shfl_xor(acc0, 32, 64);
    acc1 += __shfl_xor(acc1, 32, 64);
    acc2 += __shfl_xor(acc2, 32, 64);
    acc3 += __shfl_xor(acc3, 32, 64);
    denom += __shfl_xor(denom, 32, 64);

    if (hl == 0) {
        float4 xt = *(const float4*)&x[(size_t)n * HID + c0];
        float inv = 1.0f / fmaxf(denom, 1e-12f);
        float4 o;
        o.x = xt.x + acc0 * inv;
        o.y = xt.y + acc1 * inv;
        o.z = xt.z + acc2 * inv;
        o.w = xt.w + acc3 * inv;
        *(float4*)&out[(size_t)n * HID + c0] = o;
    }
}

// ---------------- launch ----------------
extern "C" void kernel_launch(void* const* d_in, const int* in_sizes, int n_in,
                              void* d_out, int out_size, void* d_ws, size_t ws_size,
                              hipStream_t stream) {
    const float* x  = (const float*)d_in[0];
    const int*   ei = (const int*)d_in[1];
    const float* ew = (const float*)d_in[2];
    const float* W1 = (const float*)d_in[3];
    const float* b1 = (const float*)d_in[4];
    const float* W2 = (const float*)d_in[5];
    const float* b2 = (const float*)d_in[6];
    float* out = (float*)d_out;
    char* ws = (char*)d_ws;

    const size_t deg_b    = 400000;
    const size_t rowptr_b = 400016;
    const size_t cursor_b = 400000;
    const size_t eprs_b   = 4800000;     // N_EDGES * 8
    const size_t part_b   = 1568;
    const size_t pb_b     = 1568;
    const size_t Bh_b     = 65536;
    const size_t Bl_b     = 65536;

    char* p = ws;
    int* deg      = (int*)p;             p += deg_b;
    int* rowptr   = (int*)p;             p += rowptr_b;
    int* cursor   = (int*)p;             p += cursor_b;
    uint2* eprs   = (uint2*)p;           p += eprs_b;
    int* partial  = (int*)p;             p += part_b;
    int* pbase    = (int*)p;             p += pb_b;
    unsigned short* BhG = (unsigned short*)p;  p += Bh_b;
    unsigned short* BlG = (unsigned short*)p;  p += Bl_b;
    unsigned short* zbuf  = (unsigned short*)p;  p += (size_t)N_NODES * 256 * 2;  // 51.2 MB
    unsigned short* y2buf = (unsigned short*)p;                                   // 25.6 MB

    const int edge_blocks = (N_EDGES + 255) / 256;
    const int node_wave_blocks = (N_NODES * 64 + 255) / 256;
    const int gemm_blocks = (N_NODES + 63) / 64;     // 1563

    hipLaunchKernelGGL(k_prep, dim3(SCAN_NB), dim3(256), 0, stream, W1, BhG, BlG, deg);
    hipLaunchKernelGGL(k_count, dim3(edge_blocks), dim3(256), 0, stream, ei, deg);
    hipLaunchKernelGGL(k_partial, dim3(SCAN_NB), dim3(256), 0, stream, deg, partial);
    hipLaunchKernelGGL(k_scanp, dim3(1), dim3(512), 0, stream, partial, pbase);
    hipLaunchKernelGGL(k_rowptr, dim3(SCAN_NB), dim3(256), 0, stream, deg, pbase, rowptr, cursor);
    hipLaunchKernelGGL(k_fill, dim3(edge_blocks), dim3(256), 0, stream, ei, ew, cursor, eprs);
    hipLaunchKernelGGL(k_gemm, dim3(gemm_blocks), dim3(256), 0, stream, x, BhG, BlG, zbuf, y2buf);
    hipLaunchKernelGGL(k_fused, dim3(node_wave_blocks), dim3(256), 0, stream,
                       (const unsigned int*)zbuf, (const unsigned int*)y2buf,
                       rowptr, eprs, x, W1, b1, W2, b2, out);
}

// Round 7
// 279.527 us; speedup vs baseline: 3.2267x; 1.0317x over previous
//
#include <hip/hip_runtime.h>
#include <hip/hip_bf16.h>

#define N_NODES 100000
#define N_EDGES 600000
#define HID 128
#define SCAN_NB ((N_NODES + 255) / 256)   // 391

// zbuf[n] = 256 bf16: [0:128) y1 = x@W1[0:128] (gathered, src role), [128:256) xbf = bf16(x[n])
// y2buf[n] = 128 bf16: x@W1[128:256] (sequential, tgt role)
// eprs[pos] = (uint src, float-bits w) in CSR-by-target order

typedef short bf16x8 __attribute__((ext_vector_type(8)));
typedef float f32x4  __attribute__((ext_vector_type(4)));

// ---------------- helpers ----------------
__device__ inline unsigned short f2bf(float v) {
    __hip_bfloat16 h = __float2bfloat16(v);
    return *(unsigned short*)&h;
}
__device__ inline float bf2f(unsigned short s) {
    unsigned int u = (unsigned int)s << 16;
    return __uint_as_float(u);
}
// packed pair of bf16 -> float2 (low half = first element)
__device__ inline float2 bfpair(unsigned int u) {
    float lo = __uint_as_float(u << 16);
    float hi = __uint_as_float(u & 0xffff0000u);
    return make_float2(lo, hi);
}

// ---------------- prep: zero deg + W1[0:256] -> blocked bf16 [ks][n][kl] ----------------
__global__ __launch_bounds__(256) void k_prep(const float* __restrict__ W1,
                                              unsigned short* __restrict__ Bh,
                                              int* __restrict__ deg)
{
    int idx = blockIdx.x * 256 + threadIdx.x;
    if (idx < N_NODES) deg[idx] = 0;
    if (idx < 32768) {
        int n = idx & 255;
        int k = idx >> 8;                            // 0 .. 127
        float v = (n < HID) ? W1[k * HID + n] : W1[(HID + k) * HID + (n - HID)];
        int dst = (k >> 5) * 8192 + n * 32 + (k & 31);
        Bh[dst] = f2bf(v);
    }
}

// ---------------- K-gemm (MFMA, single-term bf16, x-prefetch) ----------------
__global__ __launch_bounds__(256) void k_gemm(const float* __restrict__ x,
                                              const unsigned short* __restrict__ BhG,
                                              unsigned short* __restrict__ zbuf,
                                              unsigned short* __restrict__ y2buf)
{
    __shared__ unsigned short Ah[64 * 32];   // [m][k] 4 KB

    const int tid  = threadIdx.x;
    const int bm   = blockIdx.x * 64;
    const int wave = tid >> 6;
    const int lane = tid & 63;
    const int q    = lane >> 4;      // 0..3
    const int ln   = lane & 15;      // 0..15

    // stage-A decode: this thread handles (rowA,f4) and (rowB,f4)
    const int rowA = tid >> 3;              // 0..31
    const int rowB = rowA + 32;             // 32..63
    const int f4   = tid & 7;               // 0..7
    const int gmA  = bm + rowA;
    const int gmB  = bm + rowB;
    const bool okA = gmA < N_NODES;
    const bool okB = gmB < N_NODES;
    const float* pxA = &x[(size_t)gmA * HID + f4 * 4];
    const float* pxB = &x[(size_t)gmB * HID + f4 * 4];

    f32x4 acc[4][4] = {};            // [mt][nt]

    float4 vA = make_float4(0.f,0.f,0.f,0.f), vB = vA;
    float4 vAn = vA, vBn = vA;
    if (okA) vA = *(const float4*)pxA;
    if (okB) vB = *(const float4*)pxB;

    for (int ks = 0; ks < 4; ++ks) {
        const int k0 = ks * 32;
        // ---- stage A: convert current chunk, store LDS + xbf half of zbuf ----
        {
            float4 v = vA;
            unsigned int ph0 = (unsigned int)f2bf(v.x) | ((unsigned int)f2bf(v.y) << 16);
            unsigned int ph1 = (unsigned int)f2bf(v.z) | ((unsigned int)f2bf(v.w) << 16);
            *(uint2*)&Ah[rowA * 32 + f4 * 4] = make_uint2(ph0, ph1);
            if (okA) *(uint2*)&zbuf[(size_t)gmA * 256 + 128 + k0 + f4 * 4] = make_uint2(ph0, ph1);
        }
        {
            float4 v = vB;
            unsigned int ph0 = (unsigned int)f2bf(v.x) | ((unsigned int)f2bf(v.y) << 16);
            unsigned int ph1 = (unsigned int)f2bf(v.z) | ((unsigned int)f2bf(v.w) << 16);
            *(uint2*)&Ah[rowB * 32 + f4 * 4] = make_uint2(ph0, ph1);
            if (okB) *(uint2*)&zbuf[(size_t)gmB * 256 + 128 + k0 + f4 * 4] = make_uint2(ph0, ph1);
        }
        __syncthreads();

        // ---- prefetch next chunk's x (hidden behind ds_read + MFMA) ----
        if (ks < 3) {
            vAn = okA ? *(const float4*)(pxA + (ks + 1) * 32) : make_float4(0.f,0.f,0.f,0.f);
            vBn = okB ? *(const float4*)(pxB + (ks + 1) * 32) : make_float4(0.f,0.f,0.f,0.f);
        }

        // ---- fragments ----
        bf16x8 ah[4], bh[4];
        #pragma unroll
        for (int mt = 0; mt < 4; ++mt) {
            ah[mt] = *(const bf16x8*)&Ah[(mt * 16 + ln) * 32 + q * 8];
        }
        #pragma unroll
        for (int nt = 0; nt < 4; ++nt) {
            bh[nt] = *(const bf16x8*)&BhG[ks * 8192 + (wave * 64 + nt * 16 + ln) * 32 + q * 8];
        }
        #pragma unroll
        for (int mt = 0; mt < 4; ++mt) {
            #pragma unroll
            for (int nt = 0; nt < 4; ++nt) {
                acc[mt][nt] = __builtin_amdgcn_mfma_f32_16x16x32_bf16(ah[mt], bh[nt], acc[mt][nt], 0, 0, 0);
            }
        }
        __syncthreads();
        vA = vAn; vB = vBn;
    }

    // ---- epilogue: C/D layout col=ln, row=q*4+r; waves 0,1 -> y1 (zbuf), waves 2,3 -> y2buf ----
    #pragma unroll
    for (int mt = 0; mt < 4; ++mt) {
        #pragma unroll
        for (int r = 0; r < 4; ++r) {
            int row = bm + mt * 16 + q * 4 + r;
            if (row < N_NODES) {
                #pragma unroll
                for (int nt = 0; nt < 4; ++nt) {
                    int col = wave * 64 + nt * 16 + ln;
                    unsigned short v = f2bf(acc[mt][nt][r]);
                    if (col < 128) zbuf[(size_t)row * 256 + col] = v;
                    else           y2buf[(size_t)row * 128 + (col - 128)] = v;
                }
            }
        }
    }
}

// ---------------- CSR build ----------------
__global__ __launch_bounds__(256) void k_count(const int* __restrict__ ei,
                                               int* __restrict__ deg)
{
    int e = blockIdx.x * blockDim.x + threadIdx.x;
    if (e < N_EDGES) atomicAdd(&deg[ei[N_EDGES + e]], 1);
}

__global__ __launch_bounds__(256) void k_partial(const int* __restrict__ deg,
                                                 int* __restrict__ partial)
{
    __shared__ int s[256];
    int t = threadIdx.x;
    int idx = blockIdx.x * 256 + t;
    s[t] = (idx < N_NODES) ? deg[idx] : 0;
    __syncthreads();
    #pragma unroll
    for (int off = 128; off > 0; off >>= 1) {
        if (t < off) s[t] += s[t + off];
        __syncthreads();
    }
    if (t == 0) partial[blockIdx.x] = s[0];
}

__global__ __launch_bounds__(512) void k_scanp(const int* __restrict__ partial,
                                               int* __restrict__ pbase)
{
    __shared__ int s[512];
    int t = threadIdx.x;
    int v = (t < SCAN_NB) ? partial[t] : 0;
    s[t] = v;
    __syncthreads();
    #pragma unroll
    for (int off = 1; off < 512; off <<= 1) {
        int u = (t >= off) ? s[t - off] : 0;
        __syncthreads();
        s[t] += u;
        __syncthreads();
    }
    if (t < SCAN_NB) pbase[t] = s[t] - v;
}

__global__ __launch_bounds__(256) void k_rowptr(const int* __restrict__ deg,
                                                const int* __restrict__ pbase,
                                                int* __restrict__ rowptr,
                                                int* __restrict__ cursor)
{
    __shared__ int s[256];
    int t = threadIdx.x;
    int b = blockIdx.x;
    int idx = b * 256 + t;
    int v = (idx < N_NODES) ? deg[idx] : 0;
    s[t] = v;
    __syncthreads();
    #pragma unroll
    for (int off = 1; off < 256; off <<= 1) {
        int u = (t >= off) ? s[t - off] : 0;
        __syncthreads();
        s[t] += u;
        __syncthreads();
    }
    if (idx < N_NODES) {
        int r = pbase[b] + s[t] - v;
        rowptr[idx] = r;
        cursor[idx] = r;
    }
    if (idx == 0) rowptr[N_NODES] = N_EDGES;
}

__global__ __launch_bounds__(256) void k_fill(const int* __restrict__ ei,
                                              const float* __restrict__ ew,
                                              int* __restrict__ cursor,
                                              uint2* __restrict__ eprs)
{
    int e = blockIdx.x * blockDim.x + threadIdx.x;
    if (e >= N_EDGES) return;
    int tgt = ei[N_EDGES + e];
    int pos = atomicAdd(&cursor[tgt], 1);
    eprs[pos] = make_uint2((unsigned int)ei[e], __float_as_uint(ew[e]));
}

// ---------------- fused scores + softmax + aggregation ----------------
// one wave per node; quarter-wave (16 lanes) per edge; lane holds 8 cols (uint4);
// 4 edges per iteration (one per quarter)
__global__ __launch_bounds__(256) void k_fused(const unsigned int* __restrict__ zu,
                                               const unsigned int* __restrict__ y2u,
                                               const int* __restrict__ rowptr,
                                               const uint2* __restrict__ eprs,
                                               const float* __restrict__ x,
                                               const float* __restrict__ W1,
                                               const float* __restrict__ b1,
                                               const float* __restrict__ W2,
                                               const float* __restrict__ b2,
                                               float* __restrict__ out)
{
    int n = (blockIdx.x * blockDim.x + threadIdx.x) >> 6;
    int lane = threadIdx.x & 63;
    if (n >= N_NODES) return;
    int ql = lane & 15;      // position within quarter: cols ql*8 .. ql*8+7
    int qi = lane >> 4;      // quarter index 0..3 (edge slot)
    int c0 = ql * 8;

    // per-lane constants for 8 cols
    uint4 uy2 = *(const uint4*)&y2u[(size_t)n * 64 + ql * 4];
    float2 y2a = bfpair(uy2.x), y2b = bfpair(uy2.y), y2c = bfpair(uy2.z), y2d = bfpair(uy2.w);
    float4 bv0 = *(const float4*)&b1[c0];
    float4 bv1 = *(const float4*)&b1[c0 + 4];
    float4 wr0 = *(const float4*)&W1[256 * HID + c0];
    float4 wr1 = *(const float4*)&W1[256 * HID + c0 + 4];
    float4 w20 = *(const float4*)&W2[c0];
    float4 w21 = *(const float4*)&W2[c0 + 4];
    float p0 = y2a.x + bv0.x, p1 = y2a.y + bv0.y, p2 = y2b.x + bv0.z, p3 = y2b.y + bv0.w;
    float p4 = y2c.x + bv1.x, p5 = y2c.y + bv1.y, p6 = y2d.x + bv1.z, p7 = y2d.y + bv1.w;
    float b2v = b2[0];

    int beg = rowptr[n], end = rowptr[n + 1];
    float a0 = 0.f, a1 = 0.f, a2 = 0.f, a3 = 0.f;
    float a4 = 0.f, a5 = 0.f, a6 = 0.f, a7 = 0.f;
    float denom = 0.f;

    for (int i = beg; i < end; i += 4) {
        int idx = i + qi;
        bool valid = idx < end;
        int ie = valid ? idx : (end - 1);
        uint2 ep = eprs[ie];
        size_t base = (size_t)ep.x * 128;
        float w = __uint_as_float(ep.y);
        uint4 uy = *(const uint4*)&zu[base + ql * 4];
        uint4 ux = *(const uint4*)&zu[base + 64 + ql * 4];

        float2 ya = bfpair(uy.x), yb = bfpair(uy.y), yc = bfpair(uy.z), yd = bfpair(uy.w);
        float h0 = fmaxf(fmaf(w, wr0.x, ya.x + p0), 0.f);
        float h1 = fmaxf(fmaf(w, wr0.y, ya.y + p1), 0.f);
        float h2 = fmaxf(fmaf(w, wr0.z, yb.x + p2), 0.f);
        float h3 = fmaxf(fmaf(w, wr0.w, yb.y + p3), 0.f);
        float h4 = fmaxf(fmaf(w, wr1.x, yc.x + p4), 0.f);
        float h5 = fmaxf(fmaf(w, wr1.y, yc.y + p5), 0.f);
        float h6 = fmaxf(fmaf(w, wr1.z, yd.x + p6), 0.f);
        float h7 = fmaxf(fmaf(w, wr1.w, yd.y + p7), 0.f);
        float s = ((h0 * w20.x + h1 * w20.y) + (h2 * w20.z + h3 * w20.w))
                + ((h4 * w21.x + h5 * w21.y) + (h6 * w21.z + h7 * w21.w));
        // reduce within quarter (xor masks 1,2,4,8 stay in the 16-lane group)
        #pragma unroll
        for (int m = 1; m <= 8; m <<= 1) s += __shfl_xor(s, m, 64);
        float es = valid ? __expf(s + b2v) : 0.f;

        float2 xa = bfpair(ux.x), xb = bfpair(ux.y), xc = bfpair(ux.z), xd = bfpair(ux.w);
        a0 = fmaf(es, xa.x, a0); a1 = fmaf(es, xa.y, a1);
        a2 = fmaf(es, xb.x, a2); a3 = fmaf(es, xb.y, a3);
        a4 = fmaf(es, xc.x, a4); a5 = fmaf(es, xc.y, a5);
        a6 = fmaf(es, xd.x, a6); a7 = fmaf(es, xd.y, a7);
        denom += es;
    }

    // merge quarters (each quarter's lane ql covers the same 8 cols)
    #pragma unroll
    for (int m = 16; m <= 32; m <<= 1) {
        a0 += __shfl_xor(a0, m, 64); a1 += __shfl_xor(a1, m, 64);
        a2 += __shfl_xor(a2, m, 64); a3 += __shfl_xor(a3, m, 64);
        a4 += __shfl_xor(a4, m, 64); a5 += __shfl_xor(a5, m, 64);
        a6 += __shfl_xor(a6, m, 64); a7 += __shfl_xor(a7, m, 64);
        denom += __shfl_xor(denom, m, 64);
    }

    if (qi == 0) {
        float4 xt0 = *(const float4*)&x[(size_t)n * HID + c0];
        float4 xt1 = *(const float4*)&x[(size_t)n * HID + c0 + 4];
        float inv = 1.0f / fmaxf(denom, 1e-12f);
        float4 o0, o1;
        o0.x = xt0.x + a0 * inv; o0.y = xt0.y + a1 * inv;
        o0.z = xt0.z + a2 * inv; o0.w = xt0.w + a3 * inv;
        o1.x = xt1.x + a4 * inv; o1.y = xt1.y + a5 * inv;
        o1.z = xt1.z + a6 * inv; o1.w = xt1.w + a7 * inv;
        *(float4*)&out[(size_t)n * HID + c0]     = o0;
        *(float4*)&out[(size_t)n * HID + c0 + 4] = o1;
    }
}

// ---------------- launch ----------------
extern "C" void kernel_launch(void* const* d_in, const int* in_sizes, int n_in,
                              void* d_out, int out_size, void* d_ws, size_t ws_size,
                              hipStream_t stream) {
    const float* x  = (const float*)d_in[0];
    const int*   ei = (const int*)d_in[1];
    const float* ew = (const float*)d_in[2];
    const float* W1 = (const float*)d_in[3];
    const float* b1 = (const float*)d_in[4];
    const float* W2 = (const float*)d_in[5];
    const float* b2 = (const float*)d_in[6];
    float* out = (float*)d_out;
    char* ws = (char*)d_ws;

    const size_t deg_b    = 400000;
    const size_t rowptr_b = 400016;
    const size_t cursor_b = 400000;
    const size_t eprs_b   = 4800000;     // N_EDGES * 8
    const size_t part_b   = 1568;
    const size_t pb_b     = 1568;
    const size_t Bh_b     = 65536;

    char* p = ws;
    int* deg      = (int*)p;             p += deg_b;
    int* rowptr   = (int*)p;             p += rowptr_b;
    int* cursor   = (int*)p;             p += cursor_b;
    uint2* eprs   = (uint2*)p;           p += eprs_b;
    int* partial  = (int*)p;             p += part_b;
    int* pbase    = (int*)p;             p += pb_b;
    unsigned short* BhG = (unsigned short*)p;  p += Bh_b;
    unsigned short* zbuf  = (unsigned short*)p;  p += (size_t)N_NODES * 256 * 2;  // 51.2 MB
    unsigned short* y2buf = (unsigned short*)p;                                   // 25.6 MB

    const int edge_blocks = (N_EDGES + 255) / 256;
    const int node_wave_blocks = (N_NODES * 64 + 255) / 256;
    const int gemm_blocks = (N_NODES + 63) / 64;     // 1563

    hipLaunchKernelGGL(k_prep, dim3(SCAN_NB), dim3(256), 0, stream, W1, BhG, deg);
    hipLaunchKernelGGL(k_count, dim3(edge_blocks), dim3(256), 0, stream, ei, deg);
    hipLaunchKernelGGL(k_partial, dim3(SCAN_NB), dim3(256), 0, stream, deg, partial);
    hipLaunchKernelGGL(k_scanp, dim3(1), dim3(512), 0, stream, partial, pbase);
    hipLaunchKernelGGL(k_rowptr, dim3(SCAN_NB), dim3(256), 0, stream, deg, pbase, rowptr, cursor);
    hipLaunchKernelGGL(k_fill, dim3(edge_blocks), dim3(256), 0, stream, ei, ew, cursor, eprs);
    hipLaunchKernelGGL(k_gemm, dim3(gemm_blocks), dim3(256), 0, stream, x, BhG, zbuf, y2buf);
    hipLaunchKernelGGL(k_fused, dim3(node_wave_blocks), dim3(256), 0, stream,
                       (const unsigned int*)zbuf, (const unsigned int*)y2buf,
                       rowptr, eprs, x, W1, b1, W2, b2, out);
}